// Round 12
// baseline (497.428 us; speedup 1.0000x reference)
//
#include <hip/hip_runtime.h>

// ---------------------------------------------------------------------------
// GCN forward. Evidence-driven design (R4-R11):
//  - agg cost ~ a*(gather instrs) + b*(lines) (R7/R8/R10 fit, a~b~9us/M).
//    H stored bf16 in 128B rows (64 feats), lane = uint2 = 4 feats:
//    F=100 -> NCH=2 (1.6M instrs, 3.2M lines), F=50 -> NCH=1.
//    chunk = blockIdx&1 XCD-affinity; slice 6.4MB (partial L2, L3 backstop).
//  - degree-sorted node permutation (counting sort, 256 bins, rank-returning
//    atomic) -> waves process equal-degree segments, killing max-vs-mean
//    divergence (E[max of 4 Poisson(16)]~22 vs 16).
//  - ONE packed 32-bit atomic per edge builds count+wsum; returned rank makes
//    CSR fill atomic-free (R10: hist 70->small). Device atomics are memory-
//    side on CDNA4 (R9) - fewer/denser is the only lever.
//  - edge (col,norm) packed i64, broadcast-loaded; A-stores nontemporal
//    (native ext_vector_type for vector NT stores - HIP float4 is rejected).
// ---------------------------------------------------------------------------

#define BT 256
#define SCAN_B 256

typedef float nfloat4 __attribute__((ext_vector_type(4)));
typedef float nfloat2 __attribute__((ext_vector_type(2)));

__device__ inline float bf_lo(unsigned int v) { return __uint_as_float(v << 16); }
__device__ inline float bf_hi(unsigned int v) { return __uint_as_float(v & 0xFFFF0000u); }
__device__ inline unsigned short f2bf(float f) {  // round-to-nearest-even
    unsigned int u = __float_as_uint(f);
    unsigned int r = u + 0x7FFFu + ((u >> 16) & 1u);
    return (unsigned short)(r >> 16);
}

// ---------------- precompute: packed histogram + rank + degree sort ----------
__global__ void zero_kernel(unsigned int* buf, int n) {
    int i = blockIdx.x * blockDim.x + threadIdx.x;
    if (i < n) buf[i] = 0u;
}

// cw[r] += (1<<24) | round(w*65536); rank[i] = old>>24 (unique ordinal in row r)
__global__ void hist_kernel(const int* __restrict__ row, const float* __restrict__ w,
                            unsigned int* cw, int* __restrict__ rank, int e) {
    int i = blockIdx.x * blockDim.x + threadIdx.x;
    if (i >= e) return;
    unsigned int wq = (unsigned int)(w[i] * 65536.0f + 0.5f);
    unsigned int old = atomicAdd(&cw[row[i]], (1u << 24) | wq);
    rank[i] = (int)(old >> 24);
}

// counts (cw>>24) -> exclusive scan into rowptr[0..n-1]; cw wsum -> dis
__global__ void scan1_kernel(const unsigned int* __restrict__ cw, int* rowptr,
                             int* bsums, float* dis, int n) {
    __shared__ int s[SCAN_B];
    int t = threadIdx.x;
    int i = blockIdx.x * SCAN_B + t;
    unsigned int cv = (i < n) ? cw[i] : 0u;
    int v = (int)(cv >> 24);
    s[t] = v;
    __syncthreads();
    for (int off = 1; off < SCAN_B; off <<= 1) {
        int x = (t >= off) ? s[t - off] : 0;
        __syncthreads();
        s[t] += x;
        __syncthreads();
    }
    if (i < n) {
        rowptr[i] = s[t] - v;  // exclusive (pre block-offset)
        float d = 1.0f + (float)(cv & 0xFFFFFFu) * (1.0f / 65536.0f);  // +self-loop
        dis[i] = rsqrtf(fmaxf(d, 1e-12f));
    }
    if (t == SCAN_B - 1) bsums[blockIdx.x] = s[t];
}

__global__ void scan2_kernel(int* bsums, int nb) {  // single block, nb <= SCAN_B
    __shared__ int s[SCAN_B];
    int t = threadIdx.x;
    int v = (t < nb) ? bsums[t] : 0;
    s[t] = v;
    __syncthreads();
    for (int off = 1; off < SCAN_B; off <<= 1) {
        int x = (t >= off) ? s[t - off] : 0;
        __syncthreads();
        s[t] += x;
        __syncthreads();
    }
    if (t < nb) bsums[t] = s[t] - v;
}

// per-node degree histogram (256 bins) with rank return, for counting sort
__global__ void nodehist_kernel(const unsigned int* __restrict__ cw, int* dbin,
                                int* __restrict__ nrank, int n) {
    int i = blockIdx.x * blockDim.x + threadIdx.x;
    if (i >= n) return;
    unsigned int deg = cw[i] >> 24;
    if (deg > 255u) deg = 255u;
    nrank[i] = atomicAdd(&dbin[deg], 1);
}

// finalize rowptr; scatter degree-sorted permutation
__global__ void scan3_kernel(int* rowptr, const int* __restrict__ bsums,
                             const unsigned int* __restrict__ cw,
                             const int* __restrict__ nrank, const int* __restrict__ dbin,
                             int* __restrict__ perm, int n, int e) {
    int i = blockIdx.x * blockDim.x + threadIdx.x;
    if (i < n) {
        rowptr[i] += bsums[i / SCAN_B];
        unsigned int deg = cw[i] >> 24;
        if (deg > 255u) deg = 255u;
        perm[dbin[deg] + nrank[i]] = i;
    }
    if (i == 0) rowptr[n] = e;
}

// atomic-free CSR fill: slot = rowptr[r] + rank[i]
__global__ void fill_kernel(const int* __restrict__ row, const int* __restrict__ col,
                            const float* __restrict__ w, const float* __restrict__ dis,
                            const int* __restrict__ rowptr, const int* __restrict__ rank,
                            long long* __restrict__ epack, int e) {
    int i = blockIdx.x * blockDim.x + threadIdx.x;
    if (i >= e) return;
    int r = row[i], c = col[i];
    float nv = dis[r] * w[i] * dis[c];
    int dst = rowptr[r] + rank[i];
    long long v = ((long long)__float_as_int(nv) << 32) | (unsigned int)c;
    __builtin_nontemporal_store(v, &epack[dst]);
}

// ---------------- register-tiled GEMM: Hc(bf16) = chunked(actin(X) @ W) ------
// X row-major fp32 [n,K] (K%4==0); output bf16 chunked Hc[c/64][n][c%64],
// 64 bf16 = 128B = two cache lines per node per chunk (uint2/lane gathers).
template <int K, int F, bool RELU_IN>
__global__ __launch_bounds__(256) void gemm_bf16_kernel(const float* __restrict__ X,
                                                        const float* __restrict__ W,
                                                        unsigned short* __restrict__ Hc, int n) {
    static_assert(K % 4 == 0, "K must be multiple of 4");
    constexpr int NCG = (F + 3) / 4;
    constexpr int FP = NCG * 4;
    constexpr int RG = 256 / NCG;
    constexpr int ROWS = RG * 4;

    __shared__ float Ws[K * FP];
    const int tid = threadIdx.x;
    for (int i = tid; i < K * FP; i += 256) {
        int k = i / FP, c = i - k * FP;
        Ws[i] = (c < F) ? W[k * F + c] : 0.f;
    }
    __syncthreads();

    const int txc = tid % NCG;
    const int tyr = tid / NCG;
    if (tyr >= RG) return;

    const int r0 = blockIdx.x * ROWS + tyr * 4;
    bool rv[4];
    const float* xrow[4];
#pragma unroll
    for (int i = 0; i < 4; ++i) {
        int r = r0 + i;
        rv[i] = (r < n);
        xrow[i] = X + (long long)(rv[i] ? r : 0) * K;
    }

    float acc[4][4] = {};
    const float* wbase = &Ws[txc * 4];
    for (int k = 0; k < K; k += 4) {
        float4 w0 = *reinterpret_cast<const float4*>(wbase + (k + 0) * FP);
        float4 w1 = *reinterpret_cast<const float4*>(wbase + (k + 1) * FP);
        float4 w2 = *reinterpret_cast<const float4*>(wbase + (k + 2) * FP);
        float4 w3 = *reinterpret_cast<const float4*>(wbase + (k + 3) * FP);
#pragma unroll
        for (int i = 0; i < 4; ++i) {
            float4 x4 = *reinterpret_cast<const float4*>(xrow[i] + k);
            if (RELU_IN) {
                x4.x = fmaxf(x4.x, 0.f); x4.y = fmaxf(x4.y, 0.f);
                x4.z = fmaxf(x4.z, 0.f); x4.w = fmaxf(x4.w, 0.f);
            }
            acc[i][0] += x4.x * w0.x + x4.y * w1.x + x4.z * w2.x + x4.w * w3.x;
            acc[i][1] += x4.x * w0.y + x4.y * w1.y + x4.z * w2.y + x4.w * w3.y;
            acc[i][2] += x4.x * w0.z + x4.y * w1.z + x4.z * w2.z + x4.w * w3.z;
            acc[i][3] += x4.x * w0.w + x4.y * w1.w + x4.z * w2.w + x4.w * w3.w;
        }
    }

    // 4-col group contiguous, 4-aligned -> within one 64-col chunk; 8B store.
    const int c0 = txc * 4;
    const int ch = c0 >> 6;
    const int off = c0 & 63;
#pragma unroll
    for (int i = 0; i < 4; ++i) {
        if (!rv[i]) continue;
        ushort4 pk;
        pk.x = f2bf(acc[i][0]); pk.y = f2bf(acc[i][1]);
        pk.z = f2bf(acc[i][2]); pk.w = f2bf(acc[i][3]);
        *reinterpret_cast<ushort4*>(&Hc[(size_t)ch * n * 64 + (size_t)(r0 + i) * 64 + off]) = pk;
    }
}

// thread-per-row GEMV for tiny F (layer 3: K=50, F=6), fp32 output stride FS.
template <int K, int F, int FS, bool RELU_IN>
__global__ __launch_bounds__(256) void gemv_rows_kernel(const float* __restrict__ X,
                                                        const float* __restrict__ W,
                                                        float* __restrict__ H, int n) {
    static_assert(K % 2 == 0, "K must be even");
    __shared__ float Ws[K * F];
    const int tid = threadIdx.x;
    for (int i = tid; i < K * F; i += 256) Ws[i] = W[i];
    __syncthreads();
    int r = blockIdx.x * 256 + tid;
    if (r >= n) return;
    float acc[F] = {};
    const float* xp = X + (long long)r * K;
    for (int k = 0; k < K; k += 2) {
        float2 x2 = *reinterpret_cast<const float2*>(xp + k);
        if (RELU_IN) { x2.x = fmaxf(x2.x, 0.f); x2.y = fmaxf(x2.y, 0.f); }
#pragma unroll
        for (int j = 0; j < F; ++j)
            acc[j] += x2.x * Ws[k * F + j] + x2.y * Ws[(k + 1) * F + j];
    }
    long long base = (long long)r * FS;
#pragma unroll
    for (int j = 0; j < F; ++j) H[base + j] = acc[j];
}

// ---------------- bf16 chunked CSR aggregation, 128B rows, degree-sorted -----
// grid.x = NCH * ceil(n/16); chunk = blockIdx.x & (NCH-1). TPN=16 lanes, lane
// loads uint2 (4 bf16 feats) -> 128B/segment = 2 lines. node = perm[sortedIdx]
// (degree-ascending) so a wave's 4 segments iterate equal trip counts.
template <int F, int NCH>
__global__ __launch_bounds__(BT) void agg_bf16_kernel(const int* __restrict__ rowptr,
                                                      const int* __restrict__ perm,
                                                      const long long* __restrict__ epack,
                                                      const unsigned int* __restrict__ H,
                                                      const float* __restrict__ dis,
                                                      const float* __restrict__ bias,
                                                      float* __restrict__ A, int n) {
    constexpr int TPN = 16, NPB = BT / TPN;
    const int chunk = blockIdx.x & (NCH - 1);
    const int nblk = blockIdx.x / NCH;
    const int sidx = nblk * NPB + threadIdx.x / TPN;
    const int lane = threadIdx.x & (TPN - 1);
    if (sidx >= n) return;
    const int node = perm[sidx];
    const uint2* __restrict__ Hc = (const uint2*)(H + (size_t)chunk * n * 32);  // 32 uints=128B/row
    const int f = chunk * 64 + 4 * lane;

    float a0 = 0.f, a1 = 0.f, a2 = 0.f, a3 = 0.f;
    int j = rowptr[node];
    const int end = rowptr[node + 1];
    for (; j + 8 <= end; j += 8) {
        long long e0 = epack[j + 0];
        long long e1 = epack[j + 1];
        long long e2 = epack[j + 2];
        long long e3 = epack[j + 3];
        long long e4 = epack[j + 4];
        long long e5 = epack[j + 5];
        long long e6 = epack[j + 6];
        long long e7 = epack[j + 7];
        uint2 v0 = Hc[(size_t)(int)e0 * 16 + lane];
        uint2 v1 = Hc[(size_t)(int)e1 * 16 + lane];
        uint2 v2 = Hc[(size_t)(int)e2 * 16 + lane];
        uint2 v3 = Hc[(size_t)(int)e3 * 16 + lane];
        uint2 v4 = Hc[(size_t)(int)e4 * 16 + lane];
        uint2 v5 = Hc[(size_t)(int)e5 * 16 + lane];
        uint2 v6 = Hc[(size_t)(int)e6 * 16 + lane];
        uint2 v7 = Hc[(size_t)(int)e7 * 16 + lane];
        float n0 = __int_as_float((int)(e0 >> 32));
        float n1 = __int_as_float((int)(e1 >> 32));
        float n2 = __int_as_float((int)(e2 >> 32));
        float n3 = __int_as_float((int)(e3 >> 32));
        float n4 = __int_as_float((int)(e4 >> 32));
        float n5 = __int_as_float((int)(e5 >> 32));
        float n6 = __int_as_float((int)(e6 >> 32));
        float n7 = __int_as_float((int)(e7 >> 32));
        a0 += n0 * bf_lo(v0.x); a1 += n0 * bf_hi(v0.x); a2 += n0 * bf_lo(v0.y); a3 += n0 * bf_hi(v0.y);
        a0 += n1 * bf_lo(v1.x); a1 += n1 * bf_hi(v1.x); a2 += n1 * bf_lo(v1.y); a3 += n1 * bf_hi(v1.y);
        a0 += n2 * bf_lo(v2.x); a1 += n2 * bf_hi(v2.x); a2 += n2 * bf_lo(v2.y); a3 += n2 * bf_hi(v2.y);
        a0 += n3 * bf_lo(v3.x); a1 += n3 * bf_hi(v3.x); a2 += n3 * bf_lo(v3.y); a3 += n3 * bf_hi(v3.y);
        a0 += n4 * bf_lo(v4.x); a1 += n4 * bf_hi(v4.x); a2 += n4 * bf_lo(v4.y); a3 += n4 * bf_hi(v4.y);
        a0 += n5 * bf_lo(v5.x); a1 += n5 * bf_hi(v5.x); a2 += n5 * bf_lo(v5.y); a3 += n5 * bf_hi(v5.y);
        a0 += n6 * bf_lo(v6.x); a1 += n6 * bf_hi(v6.x); a2 += n6 * bf_lo(v6.y); a3 += n6 * bf_hi(v6.y);
        a0 += n7 * bf_lo(v7.x); a1 += n7 * bf_hi(v7.x); a2 += n7 * bf_lo(v7.y); a3 += n7 * bf_hi(v7.y);
    }
    for (; j < end; ++j) {
        long long ev = epack[j];
        uint2 v = Hc[(size_t)(int)ev * 16 + lane];
        float nv = __int_as_float((int)(ev >> 32));
        a0 += nv * bf_lo(v.x); a1 += nv * bf_hi(v.x);
        a2 += nv * bf_lo(v.y); a3 += nv * bf_hi(v.y);
    }
    float d = dis[node];
    float d2 = d * d;
    uint2 hs = Hc[(size_t)node * 16 + lane];
    float o0 = 0.f, o1 = 0.f, o2 = 0.f, o3 = 0.f;
    if (f < F) o0 = bias[f] + d2 * bf_lo(hs.x) + a0;
    if (f + 1 < F) o1 = bias[f + 1] + d2 * bf_hi(hs.x) + a1;
    if (f + 2 < F) o2 = bias[f + 2] + d2 * bf_lo(hs.y) + a2;
    if (f + 3 < F) o3 = bias[f + 3] + d2 * bf_hi(hs.y) + a3;
    float* ap = &A[(size_t)node * F + f];
    if constexpr (F % 4 == 0) {
        if (f + 3 < F) {
            nfloat4 o = {o0, o1, o2, o3};
            __builtin_nontemporal_store(o, (nfloat4*)ap);
        } else {
            if (f < F) __builtin_nontemporal_store(o0, ap);
            if (f + 1 < F) __builtin_nontemporal_store(o1, ap + 1);
            if (f + 2 < F) __builtin_nontemporal_store(o2, ap + 2);
            if (f + 3 < F) __builtin_nontemporal_store(o3, ap + 3);
        }
    } else {
        // F%2==0 assumed: 8B-aligned float2 stores
        if (f + 1 < F) {
            nfloat2 o = {o0, o1};
            __builtin_nontemporal_store(o, (nfloat2*)ap);
        } else if (f < F) {
            __builtin_nontemporal_store(o0, ap);
        }
        if (f + 3 < F) {
            nfloat2 o = {o2, o3};
            __builtin_nontemporal_store(o, (nfloat2*)(ap + 2));
        } else if (f + 2 < F) {
            __builtin_nontemporal_store(o2, ap + 2);
        }
    }
}

// per-node agg for tiny F (fp32 H, row stride 8 = 32B aligned), degree-sorted
template <int F, int TPN>
__global__ __launch_bounds__(BT) void agg_small_kernel(const int* __restrict__ rowptr,
                                                       const int* __restrict__ perm,
                                                       const long long* __restrict__ epack,
                                                       const float* __restrict__ H,
                                                       const float* __restrict__ dis,
                                                       const float* __restrict__ bias,
                                                       float* __restrict__ A, int n) {
    int gid = blockIdx.x * blockDim.x + threadIdx.x;
    int sidx = gid / TPN;
    int lane = threadIdx.x & (TPN - 1);
    if (sidx >= n) return;
    int node = perm[sidx];
    bool active = (lane < F);
    float acc = 0.f;
    int j = rowptr[node];
    const int end = rowptr[node + 1];
    for (; j + 4 <= end; j += 4) {
        long long e0 = epack[j + 0];
        long long e1 = epack[j + 1];
        long long e2 = epack[j + 2];
        long long e3 = epack[j + 3];
        if (active) {
            float h0 = H[(size_t)(int)e0 * 8 + lane];
            float h1 = H[(size_t)(int)e1 * 8 + lane];
            float h2 = H[(size_t)(int)e2 * 8 + lane];
            float h3 = H[(size_t)(int)e3 * 8 + lane];
            acc += __int_as_float((int)(e0 >> 32)) * h0;
            acc += __int_as_float((int)(e1 >> 32)) * h1;
            acc += __int_as_float((int)(e2 >> 32)) * h2;
            acc += __int_as_float((int)(e3 >> 32)) * h3;
        }
    }
    for (; j < end; ++j) {
        long long ev = epack[j];
        if (active) acc += __int_as_float((int)(ev >> 32)) * H[(size_t)(int)ev * 8 + lane];
    }
    if (active) {
        float d = dis[node];
        float v = bias[lane] + d * d * H[(size_t)node * 8 + lane] + acc;
        __builtin_nontemporal_store(v, &A[(size_t)node * F + lane]);
    }
}

// ---------------------------------------------------------------------------
extern "C" void kernel_launch(void* const* d_in, const int* in_sizes, int n_in,
                              void* d_out, int out_size, void* d_ws, size_t ws_size,
                              hipStream_t stream) {
    const float* x  = (const float*)d_in[0];
    const int*   ei = (const int*)d_in[1];
    const float* ew = (const float*)d_in[2];
    const float* W0 = (const float*)d_in[3];
    const float* b0 = (const float*)d_in[4];
    const float* W1 = (const float*)d_in[5];
    const float* b1 = (const float*)d_in[6];
    const float* W2 = (const float*)d_in[7];
    const float* b2 = (const float*)d_in[8];
    const float* W3 = (const float*)d_in[9];
    const float* b3 = (const float*)d_in[10];
    float* out = (float*)d_out;

    const int N = in_sizes[0] / 128;  // 50000
    const int E = in_sizes[1] / 2;    // 800000
    const int* row = ei;
    const int* col = ei + E;

    const int NB = (N + SCAN_B - 1) / SCAN_B;
    const int blocksN = (N + BT - 1) / BT;
    const int blocksE = (E + BT - 1) / BT;

    // workspace, 64B-aligned sections
    char* p = (char*)d_ws;
    auto alloc = [&](size_t bytes) {
        p = (char*)(((uintptr_t)p + 63) & ~(uintptr_t)63);
        void* r = (void*)p;
        p += bytes;
        return r;
    };
    float* dis    = (float*)alloc((size_t)N * 4);
    int*   rowptr = (int*)alloc((size_t)(N + 2) * 4);
    int*   bsums  = (int*)alloc(SCAN_B * 4);
    unsigned int* cw = (unsigned int*)alloc((size_t)(N + 256) * 4);  // cw[N] + dbin[256]
    int*   dbin   = (int*)(cw + N);
    int*   nrank  = (int*)alloc((size_t)N * 4);
    int*   perm   = (int*)alloc((size_t)N * 4);
    int*   rank   = (int*)alloc((size_t)E * 4);
    long long* epack = (long long*)alloc((size_t)E * 8);
    unsigned short* bufA = (unsigned short*)alloc((size_t)N * 128 * 2);  // chunked bf16 H
    float* bufB   = (float*)alloc((size_t)N * 100 * 4);                  // fp32 A
    float* bufAf  = (float*)bufA;  // layer-3 fp32 H3[N,8] aliases bufA

    // ---- CSR + norm + degree-sort precompute ----
    zero_kernel<<<(N + 256 + BT - 1) / BT, BT, 0, stream>>>(cw, N + 256);
    hist_kernel<<<blocksE, BT, 0, stream>>>(row, ew, cw, rank, E);
    scan1_kernel<<<NB, SCAN_B, 0, stream>>>(cw, rowptr, bsums, dis, N);
    nodehist_kernel<<<blocksN, BT, 0, stream>>>(cw, dbin, nrank, N);
    scan2_kernel<<<1, SCAN_B, 0, stream>>>(bsums, NB);
    scan2_kernel<<<1, SCAN_B, 0, stream>>>(dbin, 256);
    scan3_kernel<<<blocksN, BT, 0, stream>>>(rowptr, bsums, cw, nrank, dbin, perm, N, E);
    fill_kernel<<<blocksE, BT, 0, stream>>>(row, col, ew, dis, rowptr, rank, epack, E);

    // GEMM rows/block: F=100 -> NCG=25, ROWS=40; F=50 -> NCG=13, ROWS=76
    const int g100_blocks = (N + 39) / 40;
    const int g50_blocks  = (N + 75) / 76;

    const int agg100_blocks = 2 * ((N + 15) / 16);  // NCH=2
    const int agg50_blocks  = 1 * ((N + 15) / 16);  // NCH=1
    const int agg6_blocks   = (N * 8 + BT - 1) / BT;

    // ---- layer 0: x(128) -> 100 ----
    gemm_bf16_kernel<128, 100, false><<<g100_blocks, 256, 0, stream>>>(x, W0, bufA, N);
    agg_bf16_kernel<100, 2><<<agg100_blocks, BT, 0, stream>>>(rowptr, perm, epack, (const unsigned int*)bufA, dis, b0, bufB, N);

    // ---- layer 1: 100 -> 100 ----
    gemm_bf16_kernel<100, 100, true><<<g100_blocks, 256, 0, stream>>>(bufB, W1, bufA, N);
    agg_bf16_kernel<100, 2><<<agg100_blocks, BT, 0, stream>>>(rowptr, perm, epack, (const unsigned int*)bufA, dis, b1, bufB, N);

    // ---- layer 2: 100 -> 50 ----
    gemm_bf16_kernel<100, 50, true><<<g50_blocks, 256, 0, stream>>>(bufB, W2, bufA, N);
    agg_bf16_kernel<50, 1><<<agg50_blocks, BT, 0, stream>>>(rowptr, perm, epack, (const unsigned int*)bufA, dis, b2, bufB, N);

    // ---- layer 3: 50 -> 6 ----
    gemv_rows_kernel<50, 6, 8, true><<<(N + 255) / 256, 256, 0, stream>>>(bufB, W3, bufAf, N);
    agg_small_kernel<6, 8><<<agg6_blocks, BT, 0, stream>>>(rowptr, perm, epack, bufAf, dis, b3, out, N);
}

// Round 13
// 365.378 us; speedup vs baseline: 1.3614x; 1.3614x over previous
//
#include <hip/hip_runtime.h>

// ---------------------------------------------------------------------------
// GCN forward. Evidence-driven design (R4-R13):
//  - agg cost ~ a*(gather instrs) + b*(lines). H stored bf16 in 128B rows
//    (64 feats), lane = uint2 = 4 feats: F=100 -> NCH=2, F=50 -> NCH=1.
//  - degree-sorted node permutation -> waves carry equal-degree segments.
//    Histogram for the sort is HIERARCHICAL (LDS-local ranks + one global
//    atomic per block/bin): R12's flat version serialized 5k same-address
//    rank-returning atomics at the memory-side coherence point (131us!).
//  - ONE packed 32-bit atomic per edge builds count+wsum; returned rank makes
//    CSR fill atomic-free. Device atomics are memory-side on CDNA4 (R9).
//  - edge (col,norm) packed i64, broadcast-loaded; A-stores nontemporal
//    (native ext_vector_type for vector NT stores).
// ---------------------------------------------------------------------------

#define BT 256
#define SCAN_B 256

typedef float nfloat4 __attribute__((ext_vector_type(4)));
typedef float nfloat2 __attribute__((ext_vector_type(2)));

__device__ inline float bf_lo(unsigned int v) { return __uint_as_float(v << 16); }
__device__ inline float bf_hi(unsigned int v) { return __uint_as_float(v & 0xFFFF0000u); }
__device__ inline unsigned short f2bf(float f) {  // round-to-nearest-even
    unsigned int u = __float_as_uint(f);
    unsigned int r = u + 0x7FFFu + ((u >> 16) & 1u);
    return (unsigned short)(r >> 16);
}

// ---------------- precompute: packed histogram + rank + degree sort ----------
__global__ void zero_kernel(unsigned int* buf, int n) {
    int i = blockIdx.x * blockDim.x + threadIdx.x;
    if (i < n) buf[i] = 0u;
}

// cw[r] += (1<<24) | round(w*65536); rank[i] = old>>24 (unique ordinal in row r)
__global__ void hist_kernel(const int* __restrict__ row, const float* __restrict__ w,
                            unsigned int* cw, int* __restrict__ rank, int e) {
    int i = blockIdx.x * blockDim.x + threadIdx.x;
    if (i >= e) return;
    unsigned int wq = (unsigned int)(w[i] * 65536.0f + 0.5f);
    unsigned int old = atomicAdd(&cw[row[i]], (1u << 24) | wq);
    rank[i] = (int)(old >> 24);
}

// counts (cw>>24) -> exclusive scan into rowptr[0..n-1]; cw wsum -> dis
__global__ void scan1_kernel(const unsigned int* __restrict__ cw, int* rowptr,
                             int* bsums, float* dis, int n) {
    __shared__ int s[SCAN_B];
    int t = threadIdx.x;
    int i = blockIdx.x * SCAN_B + t;
    unsigned int cv = (i < n) ? cw[i] : 0u;
    int v = (int)(cv >> 24);
    s[t] = v;
    __syncthreads();
    for (int off = 1; off < SCAN_B; off <<= 1) {
        int x = (t >= off) ? s[t - off] : 0;
        __syncthreads();
        s[t] += x;
        __syncthreads();
    }
    if (i < n) {
        rowptr[i] = s[t] - v;  // exclusive (pre block-offset)
        float d = 1.0f + (float)(cv & 0xFFFFFFu) * (1.0f / 65536.0f);  // +self-loop
        dis[i] = rsqrtf(fmaxf(d, 1e-12f));
    }
    if (t == SCAN_B - 1) bsums[blockIdx.x] = s[t];
}

__global__ void scan2_kernel(int* bsums, int nb) {  // single block, nb <= SCAN_B
    __shared__ int s[SCAN_B];
    int t = threadIdx.x;
    int v = (t < nb) ? bsums[t] : 0;
    s[t] = v;
    __syncthreads();
    for (int off = 1; off < SCAN_B; off <<= 1) {
        int x = (t >= off) ? s[t - off] : 0;
        __syncthreads();
        s[t] += x;
        __syncthreads();
    }
    if (t < nb) bsums[t] = s[t] - v;
}

// hierarchical per-node degree histogram (256 bins) with rank return:
// LDS-local ranks (CU-local atomics) + ONE global atomic per (block, bin).
__global__ __launch_bounds__(256) void nodehist_kernel(const unsigned int* __restrict__ cw,
                                                       int* dbin, int* __restrict__ nrank, int n) {
    __shared__ int lbin[256];
    __shared__ int lbase[256];
    const int t = threadIdx.x;
    lbin[t] = 0;
    __syncthreads();
    const int i = blockIdx.x * 256 + t;
    unsigned int deg = 0u;
    int lr = 0;
    const bool valid = (i < n);
    if (valid) {
        deg = cw[i] >> 24;
        if (deg > 255u) deg = 255u;
        lr = atomicAdd(&lbin[deg], 1);  // LDS atomic -> local rank
    }
    __syncthreads();
    int c = lbin[t];
    lbase[t] = (c > 0) ? atomicAdd(&dbin[t], c) : 0;  // one global atomic per bin
    __syncthreads();
    if (valid) nrank[i] = lbase[deg] + lr;
}

// finalize rowptr; scatter degree-sorted permutation
__global__ void scan3_kernel(int* rowptr, const int* __restrict__ bsums,
                             const unsigned int* __restrict__ cw,
                             const int* __restrict__ nrank, const int* __restrict__ dbin,
                             int* __restrict__ perm, int n, int e) {
    int i = blockIdx.x * blockDim.x + threadIdx.x;
    if (i < n) {
        rowptr[i] += bsums[i / SCAN_B];
        unsigned int deg = cw[i] >> 24;
        if (deg > 255u) deg = 255u;
        perm[dbin[deg] + nrank[i]] = i;
    }
    if (i == 0) rowptr[n] = e;
}

// atomic-free CSR fill: slot = rowptr[r] + rank[i]
__global__ void fill_kernel(const int* __restrict__ row, const int* __restrict__ col,
                            const float* __restrict__ w, const float* __restrict__ dis,
                            const int* __restrict__ rowptr, const int* __restrict__ rank,
                            long long* __restrict__ epack, int e) {
    int i = blockIdx.x * blockDim.x + threadIdx.x;
    if (i >= e) return;
    int r = row[i], c = col[i];
    float nv = dis[r] * w[i] * dis[c];
    int dst = rowptr[r] + rank[i];
    long long v = ((long long)__float_as_int(nv) << 32) | (unsigned int)c;
    __builtin_nontemporal_store(v, &epack[dst]);
}

// ---------------- register-tiled GEMM: Hc(bf16) = chunked(actin(X) @ W) ------
// X row-major fp32 [n,K] (K%4==0); output bf16 chunked Hc[c/64][n][c%64],
// 64 bf16 = 128B = two cache lines per node per chunk (uint2/lane gathers).
template <int K, int F, bool RELU_IN>
__global__ __launch_bounds__(256) void gemm_bf16_kernel(const float* __restrict__ X,
                                                        const float* __restrict__ W,
                                                        unsigned short* __restrict__ Hc, int n) {
    static_assert(K % 4 == 0, "K must be multiple of 4");
    constexpr int NCG = (F + 3) / 4;
    constexpr int FP = NCG * 4;
    constexpr int RG = 256 / NCG;
    constexpr int ROWS = RG * 4;

    __shared__ float Ws[K * FP];
    const int tid = threadIdx.x;
    for (int i = tid; i < K * FP; i += 256) {
        int k = i / FP, c = i - k * FP;
        Ws[i] = (c < F) ? W[k * F + c] : 0.f;
    }
    __syncthreads();

    const int txc = tid % NCG;
    const int tyr = tid / NCG;
    if (tyr >= RG) return;

    const int r0 = blockIdx.x * ROWS + tyr * 4;
    bool rv[4];
    const float* xrow[4];
#pragma unroll
    for (int i = 0; i < 4; ++i) {
        int r = r0 + i;
        rv[i] = (r < n);
        xrow[i] = X + (long long)(rv[i] ? r : 0) * K;
    }

    float acc[4][4] = {};
    const float* wbase = &Ws[txc * 4];
    for (int k = 0; k < K; k += 4) {
        float4 w0 = *reinterpret_cast<const float4*>(wbase + (k + 0) * FP);
        float4 w1 = *reinterpret_cast<const float4*>(wbase + (k + 1) * FP);
        float4 w2 = *reinterpret_cast<const float4*>(wbase + (k + 2) * FP);
        float4 w3 = *reinterpret_cast<const float4*>(wbase + (k + 3) * FP);
#pragma unroll
        for (int i = 0; i < 4; ++i) {
            float4 x4 = *reinterpret_cast<const float4*>(xrow[i] + k);
            if (RELU_IN) {
                x4.x = fmaxf(x4.x, 0.f); x4.y = fmaxf(x4.y, 0.f);
                x4.z = fmaxf(x4.z, 0.f); x4.w = fmaxf(x4.w, 0.f);
            }
            acc[i][0] += x4.x * w0.x + x4.y * w1.x + x4.z * w2.x + x4.w * w3.x;
            acc[i][1] += x4.x * w0.y + x4.y * w1.y + x4.z * w2.y + x4.w * w3.y;
            acc[i][2] += x4.x * w0.z + x4.y * w1.z + x4.z * w2.z + x4.w * w3.z;
            acc[i][3] += x4.x * w0.w + x4.y * w1.w + x4.z * w2.w + x4.w * w3.w;
        }
    }

    // 4-col group contiguous, 4-aligned -> within one 64-col chunk; 8B store.
    const int c0 = txc * 4;
    const int ch = c0 >> 6;
    const int off = c0 & 63;
#pragma unroll
    for (int i = 0; i < 4; ++i) {
        if (!rv[i]) continue;
        ushort4 pk;
        pk.x = f2bf(acc[i][0]); pk.y = f2bf(acc[i][1]);
        pk.z = f2bf(acc[i][2]); pk.w = f2bf(acc[i][3]);
        *reinterpret_cast<ushort4*>(&Hc[(size_t)ch * n * 64 + (size_t)(r0 + i) * 64 + off]) = pk;
    }
}

// thread-per-row GEMV for tiny F (layer 3: K=50, F=6), fp32 output stride FS.
template <int K, int F, int FS, bool RELU_IN>
__global__ __launch_bounds__(256) void gemv_rows_kernel(const float* __restrict__ X,
                                                        const float* __restrict__ W,
                                                        float* __restrict__ H, int n) {
    static_assert(K % 2 == 0, "K must be even");
    __shared__ float Ws[K * F];
    const int tid = threadIdx.x;
    for (int i = tid; i < K * F; i += 256) Ws[i] = W[i];
    __syncthreads();
    int r = blockIdx.x * 256 + tid;
    if (r >= n) return;
    float acc[F] = {};
    const float* xp = X + (long long)r * K;
    for (int k = 0; k < K; k += 2) {
        float2 x2 = *reinterpret_cast<const float2*>(xp + k);
        if (RELU_IN) { x2.x = fmaxf(x2.x, 0.f); x2.y = fmaxf(x2.y, 0.f); }
#pragma unroll
        for (int j = 0; j < F; ++j)
            acc[j] += x2.x * Ws[k * F + j] + x2.y * Ws[(k + 1) * F + j];
    }
    long long base = (long long)r * FS;
#pragma unroll
    for (int j = 0; j < F; ++j) H[base + j] = acc[j];
}

// ---------------- bf16 chunked CSR aggregation, 128B rows, degree-sorted -----
// grid.x = NCH * ceil(n/16); chunk = blockIdx.x & (NCH-1). TPN=16 lanes, lane
// loads uint2 (4 bf16 feats) -> 128B/segment = 2 lines. node = perm[sortedIdx]
// (degree-ascending) so a wave's 4 segments iterate equal trip counts.
template <int F, int NCH>
__global__ __launch_bounds__(BT) void agg_bf16_kernel(const int* __restrict__ rowptr,
                                                      const int* __restrict__ perm,
                                                      const long long* __restrict__ epack,
                                                      const unsigned int* __restrict__ H,
                                                      const float* __restrict__ dis,
                                                      const float* __restrict__ bias,
                                                      float* __restrict__ A, int n) {
    constexpr int TPN = 16, NPB = BT / TPN;
    const int chunk = blockIdx.x & (NCH - 1);
    const int nblk = blockIdx.x / NCH;
    const int sidx = nblk * NPB + threadIdx.x / TPN;
    const int lane = threadIdx.x & (TPN - 1);
    if (sidx >= n) return;
    const int node = perm[sidx];
    const uint2* __restrict__ Hc = (const uint2*)(H + (size_t)chunk * n * 32);  // 32 uints=128B/row
    const int f = chunk * 64 + 4 * lane;

    float a0 = 0.f, a1 = 0.f, a2 = 0.f, a3 = 0.f;
    int j = rowptr[node];
    const int end = rowptr[node + 1];
    for (; j + 8 <= end; j += 8) {
        long long e0 = epack[j + 0];
        long long e1 = epack[j + 1];
        long long e2 = epack[j + 2];
        long long e3 = epack[j + 3];
        long long e4 = epack[j + 4];
        long long e5 = epack[j + 5];
        long long e6 = epack[j + 6];
        long long e7 = epack[j + 7];
        uint2 v0 = Hc[(size_t)(int)e0 * 16 + lane];
        uint2 v1 = Hc[(size_t)(int)e1 * 16 + lane];
        uint2 v2 = Hc[(size_t)(int)e2 * 16 + lane];
        uint2 v3 = Hc[(size_t)(int)e3 * 16 + lane];
        uint2 v4 = Hc[(size_t)(int)e4 * 16 + lane];
        uint2 v5 = Hc[(size_t)(int)e5 * 16 + lane];
        uint2 v6 = Hc[(size_t)(int)e6 * 16 + lane];
        uint2 v7 = Hc[(size_t)(int)e7 * 16 + lane];
        float n0 = __int_as_float((int)(e0 >> 32));
        float n1 = __int_as_float((int)(e1 >> 32));
        float n2 = __int_as_float((int)(e2 >> 32));
        float n3 = __int_as_float((int)(e3 >> 32));
        float n4 = __int_as_float((int)(e4 >> 32));
        float n5 = __int_as_float((int)(e5 >> 32));
        float n6 = __int_as_float((int)(e6 >> 32));
        float n7 = __int_as_float((int)(e7 >> 32));
        a0 += n0 * bf_lo(v0.x); a1 += n0 * bf_hi(v0.x); a2 += n0 * bf_lo(v0.y); a3 += n0 * bf_hi(v0.y);
        a0 += n1 * bf_lo(v1.x); a1 += n1 * bf_hi(v1.x); a2 += n1 * bf_lo(v1.y); a3 += n1 * bf_hi(v1.y);
        a0 += n2 * bf_lo(v2.x); a1 += n2 * bf_hi(v2.x); a2 += n2 * bf_lo(v2.y); a3 += n2 * bf_hi(v2.y);
        a0 += n3 * bf_lo(v3.x); a1 += n3 * bf_hi(v3.x); a2 += n3 * bf_lo(v3.y); a3 += n3 * bf_hi(v3.y);
        a0 += n4 * bf_lo(v4.x); a1 += n4 * bf_hi(v4.x); a2 += n4 * bf_lo(v4.y); a3 += n4 * bf_hi(v4.y);
        a0 += n5 * bf_lo(v5.x); a1 += n5 * bf_hi(v5.x); a2 += n5 * bf_lo(v5.y); a3 += n5 * bf_hi(v5.y);
        a0 += n6 * bf_lo(v6.x); a1 += n6 * bf_hi(v6.x); a2 += n6 * bf_lo(v6.y); a3 += n6 * bf_hi(v6.y);
        a0 += n7 * bf_lo(v7.x); a1 += n7 * bf_hi(v7.x); a2 += n7 * bf_lo(v7.y); a3 += n7 * bf_hi(v7.y);
    }
    for (; j < end; ++j) {
        long long ev = epack[j];
        uint2 v = Hc[(size_t)(int)ev * 16 + lane];
        float nv = __int_as_float((int)(ev >> 32));
        a0 += nv * bf_lo(v.x); a1 += nv * bf_hi(v.x);
        a2 += nv * bf_lo(v.y); a3 += nv * bf_hi(v.y);
    }
    float d = dis[node];
    float d2 = d * d;
    uint2 hs = Hc[(size_t)node * 16 + lane];
    float o0 = 0.f, o1 = 0.f, o2 = 0.f, o3 = 0.f;
    if (f < F) o0 = bias[f] + d2 * bf_lo(hs.x) + a0;
    if (f + 1 < F) o1 = bias[f + 1] + d2 * bf_hi(hs.x) + a1;
    if (f + 2 < F) o2 = bias[f + 2] + d2 * bf_lo(hs.y) + a2;
    if (f + 3 < F) o3 = bias[f + 3] + d2 * bf_hi(hs.y) + a3;
    float* ap = &A[(size_t)node * F + f];
    if constexpr (F % 4 == 0) {
        if (f + 3 < F) {
            nfloat4 o = {o0, o1, o2, o3};
            __builtin_nontemporal_store(o, (nfloat4*)ap);
        } else {
            if (f < F) __builtin_nontemporal_store(o0, ap);
            if (f + 1 < F) __builtin_nontemporal_store(o1, ap + 1);
            if (f + 2 < F) __builtin_nontemporal_store(o2, ap + 2);
            if (f + 3 < F) __builtin_nontemporal_store(o3, ap + 3);
        }
    } else {
        // F%2==0 assumed: 8B-aligned float2 stores
        if (f + 1 < F) {
            nfloat2 o = {o0, o1};
            __builtin_nontemporal_store(o, (nfloat2*)ap);
        } else if (f < F) {
            __builtin_nontemporal_store(o0, ap);
        }
        if (f + 3 < F) {
            nfloat2 o = {o2, o3};
            __builtin_nontemporal_store(o, (nfloat2*)(ap + 2));
        } else if (f + 2 < F) {
            __builtin_nontemporal_store(o2, ap + 2);
        }
    }
}

// per-node agg for tiny F (fp32 H, row stride 8 = 32B aligned), degree-sorted
template <int F, int TPN>
__global__ __launch_bounds__(BT) void agg_small_kernel(const int* __restrict__ rowptr,
                                                       const int* __restrict__ perm,
                                                       const long long* __restrict__ epack,
                                                       const float* __restrict__ H,
                                                       const float* __restrict__ dis,
                                                       const float* __restrict__ bias,
                                                       float* __restrict__ A, int n) {
    int gid = blockIdx.x * blockDim.x + threadIdx.x;
    int sidx = gid / TPN;
    int lane = threadIdx.x & (TPN - 1);
    if (sidx >= n) return;
    int node = perm[sidx];
    bool active = (lane < F);
    float acc = 0.f;
    int j = rowptr[node];
    const int end = rowptr[node + 1];
    for (; j + 4 <= end; j += 4) {
        long long e0 = epack[j + 0];
        long long e1 = epack[j + 1];
        long long e2 = epack[j + 2];
        long long e3 = epack[j + 3];
        if (active) {
            float h0 = H[(size_t)(int)e0 * 8 + lane];
            float h1 = H[(size_t)(int)e1 * 8 + lane];
            float h2 = H[(size_t)(int)e2 * 8 + lane];
            float h3 = H[(size_t)(int)e3 * 8 + lane];
            acc += __int_as_float((int)(e0 >> 32)) * h0;
            acc += __int_as_float((int)(e1 >> 32)) * h1;
            acc += __int_as_float((int)(e2 >> 32)) * h2;
            acc += __int_as_float((int)(e3 >> 32)) * h3;
        }
    }
    for (; j < end; ++j) {
        long long ev = epack[j];
        if (active) acc += __int_as_float((int)(ev >> 32)) * H[(size_t)(int)ev * 8 + lane];
    }
    if (active) {
        float d = dis[node];
        float v = bias[lane] + d * d * H[(size_t)node * 8 + lane] + acc;
        __builtin_nontemporal_store(v, &A[(size_t)node * F + lane]);
    }
}

// ---------------------------------------------------------------------------
extern "C" void kernel_launch(void* const* d_in, const int* in_sizes, int n_in,
                              void* d_out, int out_size, void* d_ws, size_t ws_size,
                              hipStream_t stream) {
    const float* x  = (const float*)d_in[0];
    const int*   ei = (const int*)d_in[1];
    const float* ew = (const float*)d_in[2];
    const float* W0 = (const float*)d_in[3];
    const float* b0 = (const float*)d_in[4];
    const float* W1 = (const float*)d_in[5];
    const float* b1 = (const float*)d_in[6];
    const float* W2 = (const float*)d_in[7];
    const float* b2 = (const float*)d_in[8];
    const float* W3 = (const float*)d_in[9];
    const float* b3 = (const float*)d_in[10];
    float* out = (float*)d_out;

    const int N = in_sizes[0] / 128;  // 50000
    const int E = in_sizes[1] / 2;    // 800000
    const int* row = ei;
    const int* col = ei + E;

    const int NB = (N + SCAN_B - 1) / SCAN_B;
    const int blocksN = (N + BT - 1) / BT;
    const int blocksE = (E + BT - 1) / BT;

    // workspace, 64B-aligned sections
    char* p = (char*)d_ws;
    auto alloc = [&](size_t bytes) {
        p = (char*)(((uintptr_t)p + 63) & ~(uintptr_t)63);
        void* r = (void*)p;
        p += bytes;
        return r;
    };
    float* dis    = (float*)alloc((size_t)N * 4);
    int*   rowptr = (int*)alloc((size_t)(N + 2) * 4);
    int*   bsums  = (int*)alloc(SCAN_B * 4);
    unsigned int* cw = (unsigned int*)alloc((size_t)(N + 256) * 4);  // cw[N] + dbin[256]
    int*   dbin   = (int*)(cw + N);
    int*   nrank  = (int*)alloc((size_t)N * 4);
    int*   perm   = (int*)alloc((size_t)N * 4);
    int*   rank   = (int*)alloc((size_t)E * 4);
    long long* epack = (long long*)alloc((size_t)E * 8);
    unsigned short* bufA = (unsigned short*)alloc((size_t)N * 128 * 2);  // chunked bf16 H
    float* bufB   = (float*)alloc((size_t)N * 100 * 4);                  // fp32 A
    float* bufAf  = (float*)bufA;  // layer-3 fp32 H3[N,8] aliases bufA

    // ---- CSR + norm + degree-sort precompute ----
    zero_kernel<<<(N + 256 + BT - 1) / BT, BT, 0, stream>>>(cw, N + 256);
    hist_kernel<<<blocksE, BT, 0, stream>>>(row, ew, cw, rank, E);
    scan1_kernel<<<NB, SCAN_B, 0, stream>>>(cw, rowptr, bsums, dis, N);
    nodehist_kernel<<<blocksN, BT, 0, stream>>>(cw, dbin, nrank, N);
    scan2_kernel<<<1, SCAN_B, 0, stream>>>(bsums, NB);
    scan2_kernel<<<1, SCAN_B, 0, stream>>>(dbin, 256);
    scan3_kernel<<<blocksN, BT, 0, stream>>>(rowptr, bsums, cw, nrank, dbin, perm, N, E);
    fill_kernel<<<blocksE, BT, 0, stream>>>(row, col, ew, dis, rowptr, rank, epack, E);

    // GEMM rows/block: F=100 -> NCG=25, ROWS=40; F=50 -> NCG=13, ROWS=76
    const int g100_blocks = (N + 39) / 40;
    const int g50_blocks  = (N + 75) / 76;

    const int agg100_blocks = 2 * ((N + 15) / 16);  // NCH=2
    const int agg50_blocks  = 1 * ((N + 15) / 16);  // NCH=1
    const int agg6_blocks   = (N * 8 + BT - 1) / BT;

    // ---- layer 0: x(128) -> 100 ----
    gemm_bf16_kernel<128, 100, false><<<g100_blocks, 256, 0, stream>>>(x, W0, bufA, N);
    agg_bf16_kernel<100, 2><<<agg100_blocks, BT, 0, stream>>>(rowptr, perm, epack, (const unsigned int*)bufA, dis, b0, bufB, N);

    // ---- layer 1: 100 -> 100 ----
    gemm_bf16_kernel<100, 100, true><<<g100_blocks, 256, 0, stream>>>(bufB, W1, bufA, N);
    agg_bf16_kernel<100, 2><<<agg100_blocks, BT, 0, stream>>>(rowptr, perm, epack, (const unsigned int*)bufA, dis, b1, bufB, N);

    // ---- layer 2: 100 -> 50 ----
    gemm_bf16_kernel<100, 50, true><<<g50_blocks, 256, 0, stream>>>(bufB, W2, bufA, N);
    agg_bf16_kernel<50, 1><<<agg50_blocks, BT, 0, stream>>>(rowptr, perm, epack, (const unsigned int*)bufA, dis, b2, bufB, N);

    // ---- layer 3: 50 -> 6 ----
    gemv_rows_kernel<50, 6, 8, true><<<(N + 255) / 256, 256, 0, stream>>>(bufB, W3, bufAf, N);
    agg_small_kernel<6, 8><<<agg6_blocks, BT, 0, stream>>>(rowptr, perm, epack, bufAf, dis, b3, out, N);
}

// Round 14
// 363.875 us; speedup vs baseline: 1.3670x; 1.0041x over previous
//
#include <hip/hip_runtime.h>

// ---------------------------------------------------------------------------
// GCN forward. Evidence-driven design (R4-R14):
//  - agg cost ~ a*instrs + b*lines (a~b~9us/M; R7/R8/R10 fit). H stored bf16
//    in 256B rows (128 feats, padded): ONE pass, TPN=16 lanes x uint4
//    (8 feats/lane) -> 0.8M gather instrs + 3.2M lines for F=100 (R13 had
//    1.6M+3.2M over 2 passes). F=50: 128B rows, uint2 lanes, one pass.
//  - degree-sorted node permutation (hierarchical LDS histogram - R12's flat
//    global version serialized same-address atomics at 131us) -> waves carry
//    equal-degree segments.
//  - ONE packed 32-bit atomic per edge (count<<24 | wsum.16.16fix); returned
//    rank makes CSR fill atomic-free. Device atomics are memory-side on CDNA4.
//  - edge (col,norm) packed i64, broadcast-loaded; A-stores nontemporal
//    (native ext_vector_type - HIP float4 rejected by the builtin).
// ---------------------------------------------------------------------------

#define BT 256
#define SCAN_B 256

typedef float nfloat4 __attribute__((ext_vector_type(4)));
typedef float nfloat2 __attribute__((ext_vector_type(2)));

__device__ inline float bf_lo(unsigned int v) { return __uint_as_float(v << 16); }
__device__ inline float bf_hi(unsigned int v) { return __uint_as_float(v & 0xFFFF0000u); }
__device__ inline unsigned short f2bf(float f) {  // round-to-nearest-even
    unsigned int u = __float_as_uint(f);
    unsigned int r = u + 0x7FFFu + ((u >> 16) & 1u);
    return (unsigned short)(r >> 16);
}

// ---------------- precompute ----------------
__global__ void zero_kernel(unsigned int* buf, int n) {
    int i = blockIdx.x * blockDim.x + threadIdx.x;
    if (i < n) buf[i] = 0u;
}

// cw[r] += (1<<24) | round(w*65536); rank[i] = old>>24 (unique ordinal in row r)
__global__ void hist_kernel(const int* __restrict__ row, const float* __restrict__ w,
                            unsigned int* cw, int* __restrict__ rank, int e) {
    int i = blockIdx.x * blockDim.x + threadIdx.x;
    if (i >= e) return;
    unsigned int wq = (unsigned int)(w[i] * 65536.0f + 0.5f);
    unsigned int old = atomicAdd(&cw[row[i]], (1u << 24) | wq);
    rank[i] = (int)(old >> 24);
}

// FUSED: block-scan of counts (rowptr excl. pre-offset) + dis + hierarchical
// degree histogram (LDS-local ranks, one global atomic per block/bin).
__global__ __launch_bounds__(SCAN_B) void nodeprep_kernel(const unsigned int* __restrict__ cw,
                                                          int* rowptr, int* bsums, float* dis,
                                                          int* dbin, int* __restrict__ nrank,
                                                          int n) {
    __shared__ int s[SCAN_B];
    __shared__ int lbin[256];
    __shared__ int lbase[256];
    const int t = threadIdx.x;
    const int i = blockIdx.x * SCAN_B + t;
    unsigned int cv = (i < n) ? cw[i] : 0u;
    const int v = (int)(cv >> 24);  // degree (8-bit field, <=255 by construction)
    lbin[t] = 0;
    s[t] = v;
    __syncthreads();
    int lr = 0;
    if (i < n) lr = atomicAdd(&lbin[v], 1);  // LDS atomic -> local rank
    __syncthreads();
    for (int off = 1; off < SCAN_B; off <<= 1) {
        int x = (t >= off) ? s[t - off] : 0;
        __syncthreads();
        s[t] += x;
        __syncthreads();
    }
    if (i < n) {
        rowptr[i] = s[t] - v;  // exclusive (pre block-offset)
        float d = 1.0f + (float)(cv & 0xFFFFFFu) * (1.0f / 65536.0f);  // +self-loop
        dis[i] = rsqrtf(fmaxf(d, 1e-12f));
    }
    if (t == SCAN_B - 1) bsums[blockIdx.x] = s[t];
    int c = lbin[t];
    lbase[t] = (c > 0) ? atomicAdd(&dbin[t], c) : 0;  // one global atomic per bin
    __syncthreads();
    if (i < n) nrank[i] = lbase[v] + lr;
}

// FUSED: exclusive-scan bsums[nb] then dbin[256], one block.
__global__ __launch_bounds__(256) void scan2both_kernel(int* bsums, int nb, int* dbin) {
    __shared__ int s[256];
    const int t = threadIdx.x;
    int v = (t < nb) ? bsums[t] : 0;
    s[t] = v;
    __syncthreads();
    for (int off = 1; off < 256; off <<= 1) {
        int x = (t >= off) ? s[t - off] : 0;
        __syncthreads();
        s[t] += x;
        __syncthreads();
    }
    if (t < nb) bsums[t] = s[t] - v;
    __syncthreads();
    int v2 = dbin[t];
    s[t] = v2;
    __syncthreads();
    for (int off = 1; off < 256; off <<= 1) {
        int x = (t >= off) ? s[t - off] : 0;
        __syncthreads();
        s[t] += x;
        __syncthreads();
    }
    dbin[t] = s[t] - v2;
}

// finalize rowptr; scatter degree-sorted permutation
__global__ void scan3_kernel(int* rowptr, const int* __restrict__ bsums,
                             const unsigned int* __restrict__ cw,
                             const int* __restrict__ nrank, const int* __restrict__ dbin,
                             int* __restrict__ perm, int n, int e) {
    int i = blockIdx.x * blockDim.x + threadIdx.x;
    if (i < n) {
        rowptr[i] += bsums[i / SCAN_B];
        unsigned int deg = cw[i] >> 24;
        perm[dbin[deg] + nrank[i]] = i;
    }
    if (i == 0) rowptr[n] = e;
}

// atomic-free CSR fill: slot = rowptr[r] + rank[i]
__global__ void fill_kernel(const int* __restrict__ row, const int* __restrict__ col,
                            const float* __restrict__ w, const float* __restrict__ dis,
                            const int* __restrict__ rowptr, const int* __restrict__ rank,
                            long long* __restrict__ epack, int e) {
    int i = blockIdx.x * blockDim.x + threadIdx.x;
    if (i >= e) return;
    int r = row[i], c = col[i];
    float nv = dis[r] * w[i] * dis[c];
    int dst = rowptr[r] + rank[i];
    long long v = ((long long)__float_as_int(nv) << 32) | (unsigned int)c;
    __builtin_nontemporal_store(v, &epack[dst]);
}

// ---------------- register-tiled GEMM: Hc(bf16, row stride RS) ----------------
// X row-major fp32 [n,K] (K%4==0); output bf16 Hc[r*RS + c], RS-padded rows.
template <int K, int F, int RS, bool RELU_IN>
__global__ __launch_bounds__(256) void gemm_bf16_kernel(const float* __restrict__ X,
                                                        const float* __restrict__ W,
                                                        unsigned short* __restrict__ Hc, int n) {
    static_assert(K % 4 == 0, "K must be multiple of 4");
    constexpr int NCG = (F + 3) / 4;
    constexpr int FP = NCG * 4;
    constexpr int RG = 256 / NCG;
    constexpr int ROWS = RG * 4;

    __shared__ float Ws[K * FP];
    const int tid = threadIdx.x;
    for (int i = tid; i < K * FP; i += 256) {
        int k = i / FP, c = i - k * FP;
        Ws[i] = (c < F) ? W[k * F + c] : 0.f;  // zero-pad cols F..FP
    }
    __syncthreads();

    const int txc = tid % NCG;
    const int tyr = tid / NCG;
    if (tyr >= RG) return;

    const int r0 = blockIdx.x * ROWS + tyr * 4;
    bool rv[4];
    const float* xrow[4];
#pragma unroll
    for (int i = 0; i < 4; ++i) {
        int r = r0 + i;
        rv[i] = (r < n);
        xrow[i] = X + (long long)(rv[i] ? r : 0) * K;
    }

    float acc[4][4] = {};
    const float* wbase = &Ws[txc * 4];
    for (int k = 0; k < K; k += 4) {
        float4 w0 = *reinterpret_cast<const float4*>(wbase + (k + 0) * FP);
        float4 w1 = *reinterpret_cast<const float4*>(wbase + (k + 1) * FP);
        float4 w2 = *reinterpret_cast<const float4*>(wbase + (k + 2) * FP);
        float4 w3 = *reinterpret_cast<const float4*>(wbase + (k + 3) * FP);
#pragma unroll
        for (int i = 0; i < 4; ++i) {
            float4 x4 = *reinterpret_cast<const float4*>(xrow[i] + k);
            if (RELU_IN) {
                x4.x = fmaxf(x4.x, 0.f); x4.y = fmaxf(x4.y, 0.f);
                x4.z = fmaxf(x4.z, 0.f); x4.w = fmaxf(x4.w, 0.f);
            }
            acc[i][0] += x4.x * w0.x + x4.y * w1.x + x4.z * w2.x + x4.w * w3.x;
            acc[i][1] += x4.x * w0.y + x4.y * w1.y + x4.z * w2.y + x4.w * w3.y;
            acc[i][2] += x4.x * w0.z + x4.y * w1.z + x4.z * w2.z + x4.w * w3.z;
            acc[i][3] += x4.x * w0.w + x4.y * w1.w + x4.z * w2.w + x4.w * w3.w;
        }
    }

    const int c0 = txc * 4;  // 4-col group, 8B-aligned store
#pragma unroll
    for (int i = 0; i < 4; ++i) {
        if (!rv[i]) continue;
        ushort4 pk;
        pk.x = f2bf(acc[i][0]); pk.y = f2bf(acc[i][1]);
        pk.z = f2bf(acc[i][2]); pk.w = f2bf(acc[i][3]);
        *reinterpret_cast<ushort4*>(&Hc[(size_t)(r0 + i) * RS + c0]) = pk;
    }
}

// thread-per-row GEMV for tiny F (layer 3: K=50, F=6), fp32 output stride FS.
template <int K, int F, int FS, bool RELU_IN>
__global__ __launch_bounds__(256) void gemv_rows_kernel(const float* __restrict__ X,
                                                        const float* __restrict__ W,
                                                        float* __restrict__ H, int n) {
    static_assert(K % 2 == 0, "K must be even");
    __shared__ float Ws[K * F];
    const int tid = threadIdx.x;
    for (int i = tid; i < K * F; i += 256) Ws[i] = W[i];
    __syncthreads();
    int r = blockIdx.x * 256 + tid;
    if (r >= n) return;
    float acc[F] = {};
    const float* xp = X + (long long)r * K;
    for (int k = 0; k < K; k += 2) {
        float2 x2 = *reinterpret_cast<const float2*>(xp + k);
        if (RELU_IN) { x2.x = fmaxf(x2.x, 0.f); x2.y = fmaxf(x2.y, 0.f); }
#pragma unroll
        for (int j = 0; j < F; ++j)
            acc[j] += x2.x * Ws[k * F + j] + x2.y * Ws[(k + 1) * F + j];
    }
    long long base = (long long)r * FS;
#pragma unroll
    for (int j = 0; j < F; ++j) H[base + j] = acc[j];
}

// ---------------- single-pass bf16 agg, 256B rows, uint4 lanes ----------------
// TPN=16 lanes, lane = uint4 = 8 bf16 feats, f = 8*lane. One pass over edges.
// node = perm[sidx] (degree-sorted). RS in bf16 (128). 4-deep unroll.
template <int F, int RS>
__global__ __launch_bounds__(BT) void agg_u4_kernel(const int* __restrict__ rowptr,
                                                    const int* __restrict__ perm,
                                                    const long long* __restrict__ epack,
                                                    const uint4* __restrict__ H,
                                                    const float* __restrict__ dis,
                                                    const float* __restrict__ bias,
                                                    float* __restrict__ A, int n) {
    constexpr int TPN = 16, NPB = BT / TPN;
    constexpr int RU4 = RS / 8;  // uint4 per row (16)
    const int sidx = blockIdx.x * NPB + threadIdx.x / TPN;
    const int lane = threadIdx.x & (TPN - 1);
    if (sidx >= n) return;
    const int node = perm[sidx];
    const int f = 8 * lane;

    float a[8] = {};
    int j = rowptr[node];
    const int end = rowptr[node + 1];
    for (; j + 4 <= end; j += 4) {
        long long e0 = epack[j + 0];
        long long e1 = epack[j + 1];
        long long e2 = epack[j + 2];
        long long e3 = epack[j + 3];
        uint4 v0 = H[(size_t)(int)e0 * RU4 + lane];
        uint4 v1 = H[(size_t)(int)e1 * RU4 + lane];
        uint4 v2 = H[(size_t)(int)e2 * RU4 + lane];
        uint4 v3 = H[(size_t)(int)e3 * RU4 + lane];
        float n0 = __int_as_float((int)(e0 >> 32));
        float n1 = __int_as_float((int)(e1 >> 32));
        float n2 = __int_as_float((int)(e2 >> 32));
        float n3 = __int_as_float((int)(e3 >> 32));
        a[0] += n0 * bf_lo(v0.x); a[1] += n0 * bf_hi(v0.x);
        a[2] += n0 * bf_lo(v0.y); a[3] += n0 * bf_hi(v0.y);
        a[4] += n0 * bf_lo(v0.z); a[5] += n0 * bf_hi(v0.z);
        a[6] += n0 * bf_lo(v0.w); a[7] += n0 * bf_hi(v0.w);
        a[0] += n1 * bf_lo(v1.x); a[1] += n1 * bf_hi(v1.x);
        a[2] += n1 * bf_lo(v1.y); a[3] += n1 * bf_hi(v1.y);
        a[4] += n1 * bf_lo(v1.z); a[5] += n1 * bf_hi(v1.z);
        a[6] += n1 * bf_lo(v1.w); a[7] += n1 * bf_hi(v1.w);
        a[0] += n2 * bf_lo(v2.x); a[1] += n2 * bf_hi(v2.x);
        a[2] += n2 * bf_lo(v2.y); a[3] += n2 * bf_hi(v2.y);
        a[4] += n2 * bf_lo(v2.z); a[5] += n2 * bf_hi(v2.z);
        a[6] += n2 * bf_lo(v2.w); a[7] += n2 * bf_hi(v2.w);
        a[0] += n3 * bf_lo(v3.x); a[1] += n3 * bf_hi(v3.x);
        a[2] += n3 * bf_lo(v3.y); a[3] += n3 * bf_hi(v3.y);
        a[4] += n3 * bf_lo(v3.z); a[5] += n3 * bf_hi(v3.z);
        a[6] += n3 * bf_lo(v3.w); a[7] += n3 * bf_hi(v3.w);
    }
    for (; j < end; ++j) {
        long long ev = epack[j];
        uint4 v = H[(size_t)(int)ev * RU4 + lane];
        float nv = __int_as_float((int)(ev >> 32));
        a[0] += nv * bf_lo(v.x); a[1] += nv * bf_hi(v.x);
        a[2] += nv * bf_lo(v.y); a[3] += nv * bf_hi(v.y);
        a[4] += nv * bf_lo(v.z); a[5] += nv * bf_hi(v.z);
        a[6] += nv * bf_lo(v.w); a[7] += nv * bf_hi(v.w);
    }
    const int valid = F - f;  // multiple of 4, or <=0 for tail lanes
    if (valid <= 0) return;
    float d = dis[node];
    float d2 = d * d;
    uint4 hs = H[(size_t)node * RU4 + lane];
    float h[8] = {bf_lo(hs.x), bf_hi(hs.x), bf_lo(hs.y), bf_hi(hs.y),
                  bf_lo(hs.z), bf_hi(hs.z), bf_lo(hs.w), bf_hi(hs.w)};
    float o[8];
#pragma unroll
    for (int k = 0; k < 8; ++k)
        o[k] = (k < valid) ? (bias[f + k] + d2 * h[k] + a[k]) : 0.f;
    float* ap = &A[(size_t)node * F + f];
    if (valid >= 4) {
        nfloat4 q = {o[0], o[1], o[2], o[3]};
        __builtin_nontemporal_store(q, (nfloat4*)ap);
    }
    if (valid >= 8) {
        nfloat4 q = {o[4], o[5], o[6], o[7]};
        __builtin_nontemporal_store(q, (nfloat4*)(ap + 4));
    }
}

// single-pass bf16 agg, 128B rows, uint2 lanes (F=50). f = 4*lane.
template <int F, int RS>
__global__ __launch_bounds__(BT) void agg_u2_kernel(const int* __restrict__ rowptr,
                                                    const int* __restrict__ perm,
                                                    const long long* __restrict__ epack,
                                                    const uint2* __restrict__ H,
                                                    const float* __restrict__ dis,
                                                    const float* __restrict__ bias,
                                                    float* __restrict__ A, int n) {
    constexpr int TPN = 16, NPB = BT / TPN;
    constexpr int RU2 = RS / 4;  // uint2 per row (16)
    const int sidx = blockIdx.x * NPB + threadIdx.x / TPN;
    const int lane = threadIdx.x & (TPN - 1);
    if (sidx >= n) return;
    const int node = perm[sidx];
    const int f = 4 * lane;

    float a0 = 0.f, a1 = 0.f, a2 = 0.f, a3 = 0.f;
    int j = rowptr[node];
    const int end = rowptr[node + 1];
    for (; j + 8 <= end; j += 8) {
        long long e0 = epack[j + 0];
        long long e1 = epack[j + 1];
        long long e2 = epack[j + 2];
        long long e3 = epack[j + 3];
        long long e4 = epack[j + 4];
        long long e5 = epack[j + 5];
        long long e6 = epack[j + 6];
        long long e7 = epack[j + 7];
        uint2 v0 = H[(size_t)(int)e0 * RU2 + lane];
        uint2 v1 = H[(size_t)(int)e1 * RU2 + lane];
        uint2 v2 = H[(size_t)(int)e2 * RU2 + lane];
        uint2 v3 = H[(size_t)(int)e3 * RU2 + lane];
        uint2 v4 = H[(size_t)(int)e4 * RU2 + lane];
        uint2 v5 = H[(size_t)(int)e5 * RU2 + lane];
        uint2 v6 = H[(size_t)(int)e6 * RU2 + lane];
        uint2 v7 = H[(size_t)(int)e7 * RU2 + lane];
        float n0 = __int_as_float((int)(e0 >> 32));
        float n1 = __int_as_float((int)(e1 >> 32));
        float n2 = __int_as_float((int)(e2 >> 32));
        float n3 = __int_as_float((int)(e3 >> 32));
        float n4 = __int_as_float((int)(e4 >> 32));
        float n5 = __int_as_float((int)(e5 >> 32));
        float n6 = __int_as_float((int)(e6 >> 32));
        float n7 = __int_as_float((int)(e7 >> 32));
        a0 += n0 * bf_lo(v0.x); a1 += n0 * bf_hi(v0.x); a2 += n0 * bf_lo(v0.y); a3 += n0 * bf_hi(v0.y);
        a0 += n1 * bf_lo(v1.x); a1 += n1 * bf_hi(v1.x); a2 += n1 * bf_lo(v1.y); a3 += n1 * bf_hi(v1.y);
        a0 += n2 * bf_lo(v2.x); a1 += n2 * bf_hi(v2.x); a2 += n2 * bf_lo(v2.y); a3 += n2 * bf_hi(v2.y);
        a0 += n3 * bf_lo(v3.x); a1 += n3 * bf_hi(v3.x); a2 += n3 * bf_lo(v3.y); a3 += n3 * bf_hi(v3.y);
        a0 += n4 * bf_lo(v4.x); a1 += n4 * bf_hi(v4.x); a2 += n4 * bf_lo(v4.y); a3 += n4 * bf_hi(v4.y);
        a0 += n5 * bf_lo(v5.x); a1 += n5 * bf_hi(v5.x); a2 += n5 * bf_lo(v5.y); a3 += n5 * bf_hi(v5.y);
        a0 += n6 * bf_lo(v6.x); a1 += n6 * bf_hi(v6.x); a2 += n6 * bf_lo(v6.y); a3 += n6 * bf_hi(v6.y);
        a0 += n7 * bf_lo(v7.x); a1 += n7 * bf_hi(v7.x); a2 += n7 * bf_lo(v7.y); a3 += n7 * bf_hi(v7.y);
    }
    for (; j < end; ++j) {
        long long ev = epack[j];
        uint2 v = H[(size_t)(int)ev * RU2 + lane];
        float nv = __int_as_float((int)(ev >> 32));
        a0 += nv * bf_lo(v.x); a1 += nv * bf_hi(v.x);
        a2 += nv * bf_lo(v.y); a3 += nv * bf_hi(v.y);
    }
    if (f >= F) return;
    float d = dis[node];
    float d2 = d * d;
    uint2 hs = H[(size_t)node * RU2 + lane];
    float o0 = 0.f, o1 = 0.f, o2 = 0.f, o3 = 0.f;
    if (f < F) o0 = bias[f] + d2 * bf_lo(hs.x) + a0;
    if (f + 1 < F) o1 = bias[f + 1] + d2 * bf_hi(hs.x) + a1;
    if (f + 2 < F) o2 = bias[f + 2] + d2 * bf_lo(hs.y) + a2;
    if (f + 3 < F) o3 = bias[f + 3] + d2 * bf_hi(hs.y) + a3;
    float* ap = &A[(size_t)node * F + f];
    if (f + 3 < F) {
        nfloat4 q = {o0, o1, o2, o3};
        __builtin_nontemporal_store(q, (nfloat4*)ap);
    } else if (f + 1 < F) {  // F%4==2 tail (F=50, f=48)
        nfloat2 q = {o0, o1};
        __builtin_nontemporal_store(q, (nfloat2*)ap);
    } else {
        __builtin_nontemporal_store(o0, ap);
    }
}

// per-node agg for tiny F (fp32 H, row stride 8), degree-sorted
template <int F, int TPN>
__global__ __launch_bounds__(BT) void agg_small_kernel(const int* __restrict__ rowptr,
                                                       const int* __restrict__ perm,
                                                       const long long* __restrict__ epack,
                                                       const float* __restrict__ H,
                                                       const float* __restrict__ dis,
                                                       const float* __restrict__ bias,
                                                       float* __restrict__ A, int n) {
    int gid = blockIdx.x * blockDim.x + threadIdx.x;
    int sidx = gid / TPN;
    int lane = threadIdx.x & (TPN - 1);
    if (sidx >= n) return;
    int node = perm[sidx];
    bool active = (lane < F);
    float acc = 0.f;
    int j = rowptr[node];
    const int end = rowptr[node + 1];
    for (; j + 4 <= end; j += 4) {
        long long e0 = epack[j + 0];
        long long e1 = epack[j + 1];
        long long e2 = epack[j + 2];
        long long e3 = epack[j + 3];
        if (active) {
            float h0 = H[(size_t)(int)e0 * 8 + lane];
            float h1 = H[(size_t)(int)e1 * 8 + lane];
            float h2 = H[(size_t)(int)e2 * 8 + lane];
            float h3 = H[(size_t)(int)e3 * 8 + lane];
            acc += __int_as_float((int)(e0 >> 32)) * h0;
            acc += __int_as_float((int)(e1 >> 32)) * h1;
            acc += __int_as_float((int)(e2 >> 32)) * h2;
            acc += __int_as_float((int)(e3 >> 32)) * h3;
        }
    }
    for (; j < end; ++j) {
        long long ev = epack[j];
        if (active) acc += __int_as_float((int)(ev >> 32)) * H[(size_t)(int)ev * 8 + lane];
    }
    if (active) {
        float d = dis[node];
        float v = bias[lane] + d * d * H[(size_t)node * 8 + lane] + acc;
        __builtin_nontemporal_store(v, &A[(size_t)node * F + lane]);
    }
}

// ---------------------------------------------------------------------------
extern "C" void kernel_launch(void* const* d_in, const int* in_sizes, int n_in,
                              void* d_out, int out_size, void* d_ws, size_t ws_size,
                              hipStream_t stream) {
    const float* x  = (const float*)d_in[0];
    const int*   ei = (const int*)d_in[1];
    const float* ew = (const float*)d_in[2];
    const float* W0 = (const float*)d_in[3];
    const float* b0 = (const float*)d_in[4];
    const float* W1 = (const float*)d_in[5];
    const float* b1 = (const float*)d_in[6];
    const float* W2 = (const float*)d_in[7];
    const float* b2 = (const float*)d_in[8];
    const float* W3 = (const float*)d_in[9];
    const float* b3 = (const float*)d_in[10];
    float* out = (float*)d_out;

    const int N = in_sizes[0] / 128;  // 50000
    const int E = in_sizes[1] / 2;    // 800000
    const int* row = ei;
    const int* col = ei + E;

    const int NB = (N + SCAN_B - 1) / SCAN_B;
    const int blocksN = (N + BT - 1) / BT;
    const int blocksE = (E + BT - 1) / BT;

    // workspace, 64B-aligned sections
    char* p = (char*)d_ws;
    auto alloc = [&](size_t bytes) {
        p = (char*)(((uintptr_t)p + 63) & ~(uintptr_t)63);
        void* r = (void*)p;
        p += bytes;
        return r;
    };
    float* dis    = (float*)alloc((size_t)N * 4);
    int*   rowptr = (int*)alloc((size_t)(N + 2) * 4);
    int*   bsums  = (int*)alloc(SCAN_B * 4);
    unsigned int* cw = (unsigned int*)alloc((size_t)(N + 256) * 4);  // cw[N] + dbin[256]
    int*   dbin   = (int*)(cw + N);
    int*   nrank  = (int*)alloc((size_t)N * 4);
    int*   perm   = (int*)alloc((size_t)N * 4);
    int*   rank   = (int*)alloc((size_t)E * 4);
    long long* epack = (long long*)alloc((size_t)E * 8);
    unsigned short* bufA = (unsigned short*)alloc((size_t)N * 128 * 2);  // bf16 H, 256B rows
    float* bufB   = (float*)alloc((size_t)N * 100 * 4);                  // fp32 A
    float* bufAf  = (float*)bufA;  // layer-3 fp32 H3[N,8] aliases bufA

    // ---- CSR + norm + degree-sort precompute ----
    zero_kernel<<<(N + 256 + BT - 1) / BT, BT, 0, stream>>>(cw, N + 256);
    hist_kernel<<<blocksE, BT, 0, stream>>>(row, ew, cw, rank, E);
    nodeprep_kernel<<<NB, SCAN_B, 0, stream>>>(cw, rowptr, bsums, dis, dbin, nrank, N);
    scan2both_kernel<<<1, 256, 0, stream>>>(bsums, NB, dbin);
    scan3_kernel<<<blocksN, BT, 0, stream>>>(rowptr, bsums, cw, nrank, dbin, perm, N, E);
    fill_kernel<<<blocksE, BT, 0, stream>>>(row, col, ew, dis, rowptr, rank, epack, E);

    // GEMM rows/block: F=100 -> NCG=25, ROWS=40; F=50 -> NCG=13, ROWS=76
    const int g100_blocks = (N + 39) / 40;
    const int g50_blocks  = (N + 75) / 76;

    const int agg_blocks  = (N + 15) / 16;  // single pass, 16 nodes/block
    const int agg6_blocks = (N * 8 + BT - 1) / BT;

    // ---- layer 0: x(128) -> 100 ----
    gemm_bf16_kernel<128, 100, 128, false><<<g100_blocks, 256, 0, stream>>>(x, W0, bufA, N);
    agg_u4_kernel<100, 128><<<agg_blocks, BT, 0, stream>>>(rowptr, perm, epack, (const uint4*)bufA, dis, b0, bufB, N);

    // ---- layer 1: 100 -> 100 ----
    gemm_bf16_kernel<100, 100, 128, true><<<g100_blocks, 256, 0, stream>>>(bufB, W1, bufA, N);
    agg_u4_kernel<100, 128><<<agg_blocks, BT, 0, stream>>>(rowptr, perm, epack, (const uint4*)bufA, dis, b1, bufB, N);

    // ---- layer 2: 100 -> 50 ----
    gemm_bf16_kernel<100, 50, 64, true><<<g50_blocks, 256, 0, stream>>>(bufB, W2, bufA, N);
    agg_u2_kernel<50, 64><<<agg_blocks, BT, 0, stream>>>(rowptr, perm, epack, (const uint2*)bufA, dis, b2, bufB, N);

    // ---- layer 3: 50 -> 6 ----
    gemv_rows_kernel<50, 6, 8, true><<<(N + 255) / 256, 256, 0, stream>>>(bufB, W3, bufAf, N);
    agg_small_kernel<6, 8><<<agg6_blocks, BT, 0, stream>>>(rowptr, perm, epack, bufAf, dis, b3, out, N);
}

// Round 15
// 330.031 us; speedup vs baseline: 1.5072x; 1.1025x over previous
//
#include <hip/hip_runtime.h>

// ---------------------------------------------------------------------------
// GCN forward. Evidence-driven design (R4-R15):
//  - GEMMs on MFMA (16x16x32 bf16): R14 counters showed fp32 vector GEMM at
//    44us, VALUBusy 36%, 1.5M LDS conflicts, MfmaUtil 0. W staged in LDS
//    pre-swizzled to B-frag layout (B[k=quad*8+j][n=lane&15], zero-padded);
//    A-frag = one 16B bf16 load (activations kept bf16 end-to-end, ReLU fused
//    into agg epilogue); C/D: row=(lane>>4)*4+reg, col=lane&15 (m89/m91).
//    K padded to 128; zeroed W pad rows neutralize garbage in A pad cols.
//  - agg: single pass, 256B bf16 rows, TPN=16 x uint4 (8 feats/lane);
//    cost ~ a*instrs + b*lines (R7/R8/R10). Degree-sorted perm (hierarchical
//    LDS histogram; flat global ranks serialized at 131us in R12).
//  - ONE packed 32-bit atomic per edge (count<<24|wsum fix16); returned rank
//    makes CSR fill atomic-free. Device atomics are memory-side on CDNA4 (R9).
//  - edge (col,norm) packed i64, broadcast-loaded; NT stores via ext_vector.
// ---------------------------------------------------------------------------

#define BT 256
#define SCAN_B 256

typedef float nfloat4 __attribute__((ext_vector_type(4)));
typedef float nfloat2 __attribute__((ext_vector_type(2)));
typedef unsigned int nuint4 __attribute__((ext_vector_type(4)));
typedef __attribute__((ext_vector_type(8))) short shortx8;   // 8 bf16 (A/B frag)
typedef __attribute__((ext_vector_type(4))) float floatx4;   // C/D frag

__device__ inline float bf_lo(unsigned int v) { return __uint_as_float(v << 16); }
__device__ inline float bf_hi(unsigned int v) { return __uint_as_float(v & 0xFFFF0000u); }
__device__ inline unsigned short f2bf(float f) {  // round-to-nearest-even
    unsigned int u = __float_as_uint(f);
    unsigned int r = u + 0x7FFFu + ((u >> 16) & 1u);
    return (unsigned short)(r >> 16);
}

// ---------------- precompute ----------------
__global__ void zero_kernel(unsigned int* buf, int n) {
    int i = blockIdx.x * blockDim.x + threadIdx.x;
    if (i < n) buf[i] = 0u;
}

__global__ void hist_kernel(const int* __restrict__ row, const float* __restrict__ w,
                            unsigned int* cw, int* __restrict__ rank, int e) {
    int i = blockIdx.x * blockDim.x + threadIdx.x;
    if (i >= e) return;
    unsigned int wq = (unsigned int)(w[i] * 65536.0f + 0.5f);
    unsigned int old = atomicAdd(&cw[row[i]], (1u << 24) | wq);
    rank[i] = (int)(old >> 24);
}

// FUSED: block-scan of counts + dis + hierarchical degree histogram
__global__ __launch_bounds__(SCAN_B) void nodeprep_kernel(const unsigned int* __restrict__ cw,
                                                          int* rowptr, int* bsums, float* dis,
                                                          int* dbin, int* __restrict__ nrank,
                                                          int n) {
    __shared__ int s[SCAN_B];
    __shared__ int lbin[256];
    __shared__ int lbase[256];
    const int t = threadIdx.x;
    const int i = blockIdx.x * SCAN_B + t;
    unsigned int cv = (i < n) ? cw[i] : 0u;
    const int v = (int)(cv >> 24);
    lbin[t] = 0;
    s[t] = v;
    __syncthreads();
    int lr = 0;
    if (i < n) lr = atomicAdd(&lbin[v], 1);
    __syncthreads();
    for (int off = 1; off < SCAN_B; off <<= 1) {
        int x = (t >= off) ? s[t - off] : 0;
        __syncthreads();
        s[t] += x;
        __syncthreads();
    }
    if (i < n) {
        rowptr[i] = s[t] - v;
        float d = 1.0f + (float)(cv & 0xFFFFFFu) * (1.0f / 65536.0f);
        dis[i] = rsqrtf(fmaxf(d, 1e-12f));
    }
    if (t == SCAN_B - 1) bsums[blockIdx.x] = s[t];
    int c = lbin[t];
    lbase[t] = (c > 0) ? atomicAdd(&dbin[t], c) : 0;
    __syncthreads();
    if (i < n) nrank[i] = lbase[v] + lr;
}

__global__ __launch_bounds__(256) void scan2both_kernel(int* bsums, int nb, int* dbin) {
    __shared__ int s[256];
    const int t = threadIdx.x;
    int v = (t < nb) ? bsums[t] : 0;
    s[t] = v;
    __syncthreads();
    for (int off = 1; off < 256; off <<= 1) {
        int x = (t >= off) ? s[t - off] : 0;
        __syncthreads();
        s[t] += x;
        __syncthreads();
    }
    if (t < nb) bsums[t] = s[t] - v;
    __syncthreads();
    int v2 = dbin[t];
    s[t] = v2;
    __syncthreads();
    for (int off = 1; off < 256; off <<= 1) {
        int x = (t >= off) ? s[t - off] : 0;
        __syncthreads();
        s[t] += x;
        __syncthreads();
    }
    dbin[t] = s[t] - v2;
}

__global__ void scan3_kernel(int* rowptr, const int* __restrict__ bsums,
                             const unsigned int* __restrict__ cw,
                             const int* __restrict__ nrank, const int* __restrict__ dbin,
                             int* __restrict__ perm, int n, int e) {
    int i = blockIdx.x * blockDim.x + threadIdx.x;
    if (i < n) {
        rowptr[i] += bsums[i / SCAN_B];
        unsigned int deg = cw[i] >> 24;
        perm[dbin[deg] + nrank[i]] = i;
    }
    if (i == 0) rowptr[n] = e;
}

__global__ void fill_kernel(const int* __restrict__ row, const int* __restrict__ col,
                            const float* __restrict__ w, const float* __restrict__ dis,
                            const int* __restrict__ rowptr, const int* __restrict__ rank,
                            long long* __restrict__ epack, int e) {
    int i = blockIdx.x * blockDim.x + threadIdx.x;
    if (i >= e) return;
    int r = row[i], c = col[i];
    float nv = dis[r] * w[i] * dis[c];
    int dst = rowptr[r] + rank[i];
    long long v = ((long long)__float_as_int(nv) << 32) | (unsigned int)c;
    __builtin_nontemporal_store(v, &epack[dst]);
}

// ---------------- MFMA GEMM: H(bf16, OUTS-stride rows) = X @ W --------------
// 16x16x32 bf16 MFMA. Block = 4 waves x 16 rows = 64 rows. W staged in LDS in
// B-frag layout: Wf[ks][nt][lane][j] = W[ks*32+(lane>>4)*8+j][nt*16+(lane&15)]
// (zero if k>=KREAL or c>=F). A-frag: lane holds X[r0+(lane&15)][k-octet].
// C/D: row=(lane>>4)*4+reg, col=lane&15 (m89/m91-verified mapping).
template <int KREAL, int KPAD, int F, bool IN_BF16, int INS, int OUTS>
__global__ __launch_bounds__(256) void gemm_mfma_kernel(const void* __restrict__ Xv,
                                                        const float* __restrict__ W,
                                                        unsigned short* __restrict__ H, int n) {
    constexpr int KS = KPAD / 32;
    constexpr int NT = (F + 15) / 16;
    __shared__ unsigned short Wf[KS * NT * 64 * 8];
    const int tid = threadIdx.x;
    for (int i = tid; i < KS * NT * 64 * 8; i += 256) {
        int j = i & 7;
        int ln = (i >> 3) & 63;
        int rest = i >> 9;
        int nt = rest % NT;
        int ks = rest / NT;
        int k = ks * 32 + ((ln >> 4) << 3) + j;
        int c = nt * 16 + (ln & 15);
        float wv = (k < KREAL && c < F) ? W[k * F + c] : 0.f;
        Wf[i] = f2bf(wv);
    }
    __syncthreads();

    const int wid = tid >> 6;
    const int lane = tid & 63;
    const int m = lane & 15;
    const int q = lane >> 4;
    const int r0 = blockIdx.x * 64 + wid * 16;
    int rowc = r0 + m;
    if (rowc > n - 1) rowc = n - 1;  // clamp loads; stores guarded

    floatx4 acc[NT];
#pragma unroll
    for (int nt = 0; nt < NT; ++nt) acc[nt] = (floatx4){0.f, 0.f, 0.f, 0.f};

    const float* Xf = (const float*)Xv;
    const unsigned short* Xb = (const unsigned short*)Xv;
#pragma unroll
    for (int ks = 0; ks < KS; ++ks) {
        shortx8 af;
        if constexpr (IN_BF16) {
            af = *(const shortx8*)&Xb[(size_t)rowc * INS + ks * 32 + q * 8];
        } else {
            const float* xp = &Xf[(size_t)rowc * INS + ks * 32 + q * 8];
            float4 xa = *(const float4*)xp;
            float4 xc = *(const float4*)(xp + 4);
            union { shortx8 s; unsigned int u[4]; } cv;
            cv.u[0] = ((unsigned int)f2bf(xa.y) << 16) | f2bf(xa.x);
            cv.u[1] = ((unsigned int)f2bf(xa.w) << 16) | f2bf(xa.z);
            cv.u[2] = ((unsigned int)f2bf(xc.y) << 16) | f2bf(xc.x);
            cv.u[3] = ((unsigned int)f2bf(xc.w) << 16) | f2bf(xc.z);
            af = cv.s;
        }
#pragma unroll
        for (int nt = 0; nt < NT; ++nt) {
            shortx8 bf = *(const shortx8*)&Wf[(((ks * NT) + nt) * 64 + lane) * 8];
            acc[nt] = __builtin_amdgcn_mfma_f32_16x16x32_bf16(af, bf, acc[nt], 0, 0, 0);
        }
    }

#pragma unroll
    for (int nt = 0; nt < NT; ++nt) {
        int c = nt * 16 + m;
        if (c >= F) continue;
#pragma unroll
        for (int r = 0; r < 4; ++r) {
            int orow = r0 + q * 4 + r;
            if (orow < n) H[(size_t)orow * OUTS + c] = f2bf(acc[nt][r]);
        }
    }
}

// thread-per-row GEMV for tiny F (layer 3: K=50, F=6), fp32 out stride FS.
template <int K, int F, int FS, bool RELU_IN>
__global__ __launch_bounds__(256) void gemv_rows_kernel(const float* __restrict__ X,
                                                        const float* __restrict__ W,
                                                        float* __restrict__ H, int n) {
    static_assert(K % 2 == 0, "K must be even");
    __shared__ float Ws[K * F];
    const int tid = threadIdx.x;
    for (int i = tid; i < K * F; i += 256) Ws[i] = W[i];
    __syncthreads();
    int r = blockIdx.x * 256 + tid;
    if (r >= n) return;
    float acc[F] = {};
    const float* xp = X + (long long)r * K;
    for (int k = 0; k < K; k += 2) {
        float2 x2 = *reinterpret_cast<const float2*>(xp + k);
        if (RELU_IN) { x2.x = fmaxf(x2.x, 0.f); x2.y = fmaxf(x2.y, 0.f); }
#pragma unroll
        for (int j = 0; j < F; ++j)
            acc[j] += x2.x * Ws[k * F + j] + x2.y * Ws[(k + 1) * F + j];
    }
    long long base = (long long)r * FS;
#pragma unroll
    for (int j = 0; j < F; ++j) H[base + j] = acc[j];
}

// ---------------- single-pass agg, 256B bf16 rows, uint4 lanes ----------------
// Output: bf16 A-rows (RSOUT ushorts, 256B) with fused ReLU - feeds MFMA GEMM.
// Pad cols (f+k>=F) written 0; pad lanes skip (poison stays, neutralized by
// zeroed W pad rows in the next GEMM).
template <int F, int RSIN, int RSOUT>
__global__ __launch_bounds__(BT) void agg_o4_kernel(const int* __restrict__ rowptr,
                                                    const int* __restrict__ perm,
                                                    const long long* __restrict__ epack,
                                                    const uint4* __restrict__ H,
                                                    const float* __restrict__ dis,
                                                    const float* __restrict__ bias,
                                                    unsigned short* __restrict__ A, int n) {
    constexpr int TPN = 16, NPB = BT / TPN;
    constexpr int RU4 = RSIN / 8;
    const int sidx = blockIdx.x * NPB + threadIdx.x / TPN;
    const int lane = threadIdx.x & (TPN - 1);
    if (sidx >= n) return;
    const int node = perm[sidx];
    const int f = 8 * lane;

    float a[8] = {};
    int j = rowptr[node];
    const int end = rowptr[node + 1];
    for (; j + 4 <= end; j += 4) {
        long long e0 = epack[j + 0];
        long long e1 = epack[j + 1];
        long long e2 = epack[j + 2];
        long long e3 = epack[j + 3];
        uint4 v0 = H[(size_t)(int)e0 * RU4 + lane];
        uint4 v1 = H[(size_t)(int)e1 * RU4 + lane];
        uint4 v2 = H[(size_t)(int)e2 * RU4 + lane];
        uint4 v3 = H[(size_t)(int)e3 * RU4 + lane];
        float n0 = __int_as_float((int)(e0 >> 32));
        float n1 = __int_as_float((int)(e1 >> 32));
        float n2 = __int_as_float((int)(e2 >> 32));
        float n3 = __int_as_float((int)(e3 >> 32));
        a[0] += n0 * bf_lo(v0.x); a[1] += n0 * bf_hi(v0.x);
        a[2] += n0 * bf_lo(v0.y); a[3] += n0 * bf_hi(v0.y);
        a[4] += n0 * bf_lo(v0.z); a[5] += n0 * bf_hi(v0.z);
        a[6] += n0 * bf_lo(v0.w); a[7] += n0 * bf_hi(v0.w);
        a[0] += n1 * bf_lo(v1.x); a[1] += n1 * bf_hi(v1.x);
        a[2] += n1 * bf_lo(v1.y); a[3] += n1 * bf_hi(v1.y);
        a[4] += n1 * bf_lo(v1.z); a[5] += n1 * bf_hi(v1.z);
        a[6] += n1 * bf_lo(v1.w); a[7] += n1 * bf_hi(v1.w);
        a[0] += n2 * bf_lo(v2.x); a[1] += n2 * bf_hi(v2.x);
        a[2] += n2 * bf_lo(v2.y); a[3] += n2 * bf_hi(v2.y);
        a[4] += n2 * bf_lo(v2.z); a[5] += n2 * bf_hi(v2.z);
        a[6] += n2 * bf_lo(v2.w); a[7] += n2 * bf_hi(v2.w);
        a[0] += n3 * bf_lo(v3.x); a[1] += n3 * bf_hi(v3.x);
        a[2] += n3 * bf_lo(v3.y); a[3] += n3 * bf_hi(v3.y);
        a[4] += n3 * bf_lo(v3.z); a[5] += n3 * bf_hi(v3.z);
        a[6] += n3 * bf_lo(v3.w); a[7] += n3 * bf_hi(v3.w);
    }
    for (; j < end; ++j) {
        long long ev = epack[j];
        uint4 v = H[(size_t)(int)ev * RU4 + lane];
        float nv = __int_as_float((int)(ev >> 32));
        a[0] += nv * bf_lo(v.x); a[1] += nv * bf_hi(v.x);
        a[2] += nv * bf_lo(v.y); a[3] += nv * bf_hi(v.y);
        a[4] += nv * bf_lo(v.z); a[5] += nv * bf_hi(v.z);
        a[6] += nv * bf_lo(v.w); a[7] += nv * bf_hi(v.w);
    }
    const int valid = F - f;
    if (valid <= 0) return;  // pad lanes: poison stays, neutralized by W k-pad
    float d = dis[node];
    float d2 = d * d;
    uint4 hs = H[(size_t)node * RU4 + lane];
    float h[8] = {bf_lo(hs.x), bf_hi(hs.x), bf_lo(hs.y), bf_hi(hs.y),
                  bf_lo(hs.z), bf_hi(hs.z), bf_lo(hs.w), bf_hi(hs.w)};
    unsigned short o[8];
#pragma unroll
    for (int k = 0; k < 8; ++k) {
        float t = (k < valid) ? fmaxf(bias[f + k] + d2 * h[k] + a[k], 0.f) : 0.f;
        o[k] = f2bf(t);
    }
    nuint4 qv;
    qv.x = ((unsigned int)o[1] << 16) | o[0];
    qv.y = ((unsigned int)o[3] << 16) | o[2];
    qv.z = ((unsigned int)o[5] << 16) | o[4];
    qv.w = ((unsigned int)o[7] << 16) | o[6];
    __builtin_nontemporal_store(qv, (nuint4*)&A[(size_t)node * RSOUT + f]);
}

// single-pass agg, 128B bf16 rows in, fp32 out (layer 2 -> gemv). f = 4*lane.
template <int F, int RSIN>
__global__ __launch_bounds__(BT) void agg_u2_kernel(const int* __restrict__ rowptr,
                                                    const int* __restrict__ perm,
                                                    const long long* __restrict__ epack,
                                                    const uint2* __restrict__ H,
                                                    const float* __restrict__ dis,
                                                    const float* __restrict__ bias,
                                                    float* __restrict__ A, int n) {
    constexpr int TPN = 16, NPB = BT / TPN;
    constexpr int RU2 = RSIN / 4;
    const int sidx = blockIdx.x * NPB + threadIdx.x / TPN;
    const int lane = threadIdx.x & (TPN - 1);
    if (sidx >= n) return;
    const int node = perm[sidx];
    const int f = 4 * lane;

    float a0 = 0.f, a1 = 0.f, a2 = 0.f, a3 = 0.f;
    int j = rowptr[node];
    const int end = rowptr[node + 1];
    for (; j + 8 <= end; j += 8) {
        long long e0 = epack[j + 0];
        long long e1 = epack[j + 1];
        long long e2 = epack[j + 2];
        long long e3 = epack[j + 3];
        long long e4 = epack[j + 4];
        long long e5 = epack[j + 5];
        long long e6 = epack[j + 6];
        long long e7 = epack[j + 7];
        uint2 v0 = H[(size_t)(int)e0 * RU2 + lane];
        uint2 v1 = H[(size_t)(int)e1 * RU2 + lane];
        uint2 v2 = H[(size_t)(int)e2 * RU2 + lane];
        uint2 v3 = H[(size_t)(int)e3 * RU2 + lane];
        uint2 v4 = H[(size_t)(int)e4 * RU2 + lane];
        uint2 v5 = H[(size_t)(int)e5 * RU2 + lane];
        uint2 v6 = H[(size_t)(int)e6 * RU2 + lane];
        uint2 v7 = H[(size_t)(int)e7 * RU2 + lane];
        float n0 = __int_as_float((int)(e0 >> 32));
        float n1 = __int_as_float((int)(e1 >> 32));
        float n2 = __int_as_float((int)(e2 >> 32));
        float n3 = __int_as_float((int)(e3 >> 32));
        float n4 = __int_as_float((int)(e4 >> 32));
        float n5 = __int_as_float((int)(e5 >> 32));
        float n6 = __int_as_float((int)(e6 >> 32));
        float n7 = __int_as_float((int)(e7 >> 32));
        a0 += n0 * bf_lo(v0.x); a1 += n0 * bf_hi(v0.x); a2 += n0 * bf_lo(v0.y); a3 += n0 * bf_hi(v0.y);
        a0 += n1 * bf_lo(v1.x); a1 += n1 * bf_hi(v1.x); a2 += n1 * bf_lo(v1.y); a3 += n1 * bf_hi(v1.y);
        a0 += n2 * bf_lo(v2.x); a1 += n2 * bf_hi(v2.x); a2 += n2 * bf_lo(v2.y); a3 += n2 * bf_hi(v2.y);
        a0 += n3 * bf_lo(v3.x); a1 += n3 * bf_hi(v3.x); a2 += n3 * bf_lo(v3.y); a3 += n3 * bf_hi(v3.y);
        a0 += n4 * bf_lo(v4.x); a1 += n4 * bf_hi(v4.x); a2 += n4 * bf_lo(v4.y); a3 += n4 * bf_hi(v4.y);
        a0 += n5 * bf_lo(v5.x); a1 += n5 * bf_hi(v5.x); a2 += n5 * bf_lo(v5.y); a3 += n5 * bf_hi(v5.y);
        a0 += n6 * bf_lo(v6.x); a1 += n6 * bf_hi(v6.x); a2 += n6 * bf_lo(v6.y); a3 += n6 * bf_hi(v6.y);
        a0 += n7 * bf_lo(v7.x); a1 += n7 * bf_hi(v7.x); a2 += n7 * bf_lo(v7.y); a3 += n7 * bf_hi(v7.y);
    }
    for (; j < end; ++j) {
        long long ev = epack[j];
        uint2 v = H[(size_t)(int)ev * RU2 + lane];
        float nv = __int_as_float((int)(ev >> 32));
        a0 += nv * bf_lo(v.x); a1 += nv * bf_hi(v.x);
        a2 += nv * bf_lo(v.y); a3 += nv * bf_hi(v.y);
    }
    if (f >= F) return;
    float d = dis[node];
    float d2 = d * d;
    uint2 hs = H[(size_t)node * RU2 + lane];
    float o0 = 0.f, o1 = 0.f, o2 = 0.f, o3 = 0.f;
    if (f < F) o0 = bias[f] + d2 * bf_lo(hs.x) + a0;
    if (f + 1 < F) o1 = bias[f + 1] + d2 * bf_hi(hs.x) + a1;
    if (f + 2 < F) o2 = bias[f + 2] + d2 * bf_lo(hs.y) + a2;
    if (f + 3 < F) o3 = bias[f + 3] + d2 * bf_hi(hs.y) + a3;
    float* ap = &A[(size_t)node * F + f];
    if (f + 3 < F) {
        nfloat4 q = {o0, o1, o2, o3};
        __builtin_nontemporal_store(q, (nfloat4*)ap);
    } else if (f + 1 < F) {  // F=50 tail at f=48
        nfloat2 q = {o0, o1};
        __builtin_nontemporal_store(q, (nfloat2*)ap);
    } else {
        __builtin_nontemporal_store(o0, ap);
    }
}

// per-node agg for tiny F (fp32 H, row stride 8), degree-sorted
template <int F, int TPN>
__global__ __launch_bounds__(BT) void agg_small_kernel(const int* __restrict__ rowptr,
                                                       const int* __restrict__ perm,
                                                       const long long* __restrict__ epack,
                                                       const float* __restrict__ H,
                                                       const float* __restrict__ dis,
                                                       const float* __restrict__ bias,
                                                       float* __restrict__ A, int n) {
    int gid = blockIdx.x * blockDim.x + threadIdx.x;
    int sidx = gid / TPN;
    int lane = threadIdx.x & (TPN - 1);
    if (sidx >= n) return;
    int node = perm[sidx];
    bool active = (lane < F);
    float acc = 0.f;
    int j = rowptr[node];
    const int end = rowptr[node + 1];
    for (; j + 4 <= end; j += 4) {
        long long e0 = epack[j + 0];
        long long e1 = epack[j + 1];
        long long e2 = epack[j + 2];
        long long e3 = epack[j + 3];
        if (active) {
            float h0 = H[(size_t)(int)e0 * 8 + lane];
            float h1 = H[(size_t)(int)e1 * 8 + lane];
            float h2 = H[(size_t)(int)e2 * 8 + lane];
            float h3 = H[(size_t)(int)e3 * 8 + lane];
            acc += __int_as_float((int)(e0 >> 32)) * h0;
            acc += __int_as_float((int)(e1 >> 32)) * h1;
            acc += __int_as_float((int)(e2 >> 32)) * h2;
            acc += __int_as_float((int)(e3 >> 32)) * h3;
        }
    }
    for (; j < end; ++j) {
        long long ev = epack[j];
        if (active) acc += __int_as_float((int)(ev >> 32)) * H[(size_t)(int)ev * 8 + lane];
    }
    if (active) {
        float d = dis[node];
        float v = bias[lane] + d * d * H[(size_t)node * 8 + lane] + acc;
        __builtin_nontemporal_store(v, &A[(size_t)node * F + lane]);
    }
}

// ---------------------------------------------------------------------------
extern "C" void kernel_launch(void* const* d_in, const int* in_sizes, int n_in,
                              void* d_out, int out_size, void* d_ws, size_t ws_size,
                              hipStream_t stream) {
    const float* x  = (const float*)d_in[0];
    const int*   ei = (const int*)d_in[1];
    const float* ew = (const float*)d_in[2];
    const float* W0 = (const float*)d_in[3];
    const float* b0 = (const float*)d_in[4];
    const float* W1 = (const float*)d_in[5];
    const float* b1 = (const float*)d_in[6];
    const float* W2 = (const float*)d_in[7];
    const float* b2 = (const float*)d_in[8];
    const float* W3 = (const float*)d_in[9];
    const float* b3 = (const float*)d_in[10];
    float* out = (float*)d_out;

    const int N = in_sizes[0] / 128;  // 50000
    const int E = in_sizes[1] / 2;    // 800000
    const int* row = ei;
    const int* col = ei + E;

    const int NB = (N + SCAN_B - 1) / SCAN_B;
    const int blocksN = (N + BT - 1) / BT;
    const int blocksE = (E + BT - 1) / BT;

    // workspace, 64B-aligned sections
    char* p = (char*)d_ws;
    auto alloc = [&](size_t bytes) {
        p = (char*)(((uintptr_t)p + 63) & ~(uintptr_t)63);
        void* r = (void*)p;
        p += bytes;
        return r;
    };
    float* dis    = (float*)alloc((size_t)N * 4);
    int*   rowptr = (int*)alloc((size_t)(N + 2) * 4);
    int*   bsums  = (int*)alloc(SCAN_B * 4);
    unsigned int* cw = (unsigned int*)alloc((size_t)(N + 256) * 4);  // cw[N] + dbin[256]
    int*   dbin   = (int*)(cw + N);
    int*   nrank  = (int*)alloc((size_t)N * 4);
    int*   perm   = (int*)alloc((size_t)N * 4);
    int*   rank   = (int*)alloc((size_t)E * 4);
    long long* epack = (long long*)alloc((size_t)E * 8);
    unsigned short* bufA = (unsigned short*)alloc((size_t)N * 128 * 2);  // H bf16, 256B rows
    unsigned short* bufB = (unsigned short*)alloc((size_t)N * 128 * 2);  // A bf16 / A3 fp32
    float* bufAf  = (float*)bufA;  // layer-3 fp32 H3[N,8] aliases bufA
    float* bufBf  = (float*)bufB;  // layer-3 fp32 A3[N,50] aliases bufB

    // ---- CSR + norm + degree-sort precompute ----
    zero_kernel<<<(N + 256 + BT - 1) / BT, BT, 0, stream>>>(cw, N + 256);
    hist_kernel<<<blocksE, BT, 0, stream>>>(row, ew, cw, rank, E);
    nodeprep_kernel<<<NB, SCAN_B, 0, stream>>>(cw, rowptr, bsums, dis, dbin, nrank, N);
    scan2both_kernel<<<1, 256, 0, stream>>>(bsums, NB, dbin);
    scan3_kernel<<<blocksN, BT, 0, stream>>>(rowptr, bsums, cw, nrank, dbin, perm, N, E);
    fill_kernel<<<blocksE, BT, 0, stream>>>(row, col, ew, dis, rowptr, rank, epack, E);

    const int gemm_blocks = (N + 63) / 64;   // 64 rows/block (4 waves x 16)
    const int agg_blocks  = (N + 15) / 16;   // 16 nodes/block
    const int agg6_blocks = (N * 8 + BT - 1) / BT;

    // ---- layer 0: x fp32 (K=128) -> H bf16 100(112) cols ----
    gemm_mfma_kernel<128, 128, 100, false, 128, 128><<<gemm_blocks, 256, 0, stream>>>(x, W0, bufA, N);
    agg_o4_kernel<100, 128, 128><<<agg_blocks, BT, 0, stream>>>(rowptr, perm, epack, (const uint4*)bufA, dis, b0, bufB, N);

    // ---- layer 1: A1 bf16 (K=100 pad 128) -> H bf16 ----
    gemm_mfma_kernel<100, 128, 100, true, 128, 128><<<gemm_blocks, 256, 0, stream>>>(bufB, W1, bufA, N);
    agg_o4_kernel<100, 128, 128><<<agg_blocks, BT, 0, stream>>>(rowptr, perm, epack, (const uint4*)bufA, dis, b1, bufB, N);

    // ---- layer 2: A2 bf16 -> H bf16 50(64) cols, then agg to fp32 A3 ----
    gemm_mfma_kernel<100, 128, 50, true, 128, 64><<<gemm_blocks, 256, 0, stream>>>(bufB, W2, bufA, N);
    agg_u2_kernel<50, 64><<<agg_blocks, BT, 0, stream>>>(rowptr, perm, epack, (const uint2*)bufA, dis, b2, bufBf, N);

    // ---- layer 3: gemv (relu on load) + small agg ----
    gemv_rows_kernel<50, 6, 8, true><<<(N + 255) / 256, 256, 0, stream>>>(bufBf, W3, bufAf, N);
    agg_small_kernel<6, 8><<<agg6_blocks, BT, 0, stream>>>(rowptr, perm, epack, bufAf, dis, b3, out, N);
}